// Round 3
// baseline (400.497 us; speedup 1.0000x reference)
//
#include <hip/hip_runtime.h>

#define NNODES 50000
#define NREL   90
#define NEDGE  800000
#define HDIM   16
#define NBASIS 30
#define NCLS   8
#define SCAN_B 256
#define NB1    ((NNODES + SCAN_B - 1) / SCAN_B)   // 196
#define BSTR   496   // padded per-src basis slice stride (480 + 16)

// ============================================================
// histogram: deg[dst*R+r]++, cnt_s[src]++, cnt_d[dst]++
// ============================================================
__global__ __launch_bounds__(256) void degcnt_kernel(const int* __restrict__ ei,
                                                     const int* __restrict__ et,
                                                     int* __restrict__ deg,
                                                     int* __restrict__ cnt_s,
                                                     int* __restrict__ cnt_d) {
    int e = blockIdx.x * blockDim.x + threadIdx.x;
    if (e >= NEDGE) return;
    int src = ei[e];
    int dst = ei[NEDGE + e];
    int r   = et[e];
    atomicAdd(&deg[dst * NREL + r], 1);
    atomicAdd(&cnt_s[src], 1);
    atomicAdd(&cnt_d[dst], 1);
}

// ---------------- generic 2-level exclusive scan over N=NNODES ----------------
__global__ __launch_bounds__(SCAN_B) void scan1_kernel(const int* __restrict__ cnt,
                                                       int* __restrict__ offs,
                                                       int* __restrict__ bsum) {
    __shared__ int tmp[SCAN_B];
    int gid = blockIdx.x * SCAN_B + threadIdx.x;
    int v = (gid < NNODES) ? cnt[gid] : 0;
    tmp[threadIdx.x] = v;
    for (int d = 1; d < SCAN_B; d <<= 1) {
        __syncthreads();
        int t = (threadIdx.x >= d) ? tmp[threadIdx.x - d] : 0;
        __syncthreads();
        tmp[threadIdx.x] += t;
    }
    __syncthreads();
    if (gid < NNODES) offs[gid] = tmp[threadIdx.x] - v;
    if (threadIdx.x == SCAN_B - 1) bsum[blockIdx.x] = tmp[SCAN_B - 1];
}

__global__ __launch_bounds__(SCAN_B) void scan2_kernel(const int* __restrict__ bsum,
                                                       int* __restrict__ bpre) {
    __shared__ int tmp[SCAN_B];
    int v = (threadIdx.x < NB1) ? bsum[threadIdx.x] : 0;
    tmp[threadIdx.x] = v;
    for (int d = 1; d < SCAN_B; d <<= 1) {
        __syncthreads();
        int t = (threadIdx.x >= d) ? tmp[threadIdx.x - d] : 0;
        __syncthreads();
        tmp[threadIdx.x] += t;
    }
    __syncthreads();
    if (threadIdx.x < NB1) bpre[threadIdx.x] = tmp[threadIdx.x] - v;
}

__global__ __launch_bounds__(SCAN_B) void scanadd_kernel(int* __restrict__ offs,
                                                         const int* __restrict__ bpre,
                                                         int* __restrict__ cursor) {
    int i = blockIdx.x * SCAN_B + threadIdx.x;
    if (i >= NNODES) return;
    int v = offs[i] + bpre[i >> 8];
    offs[i] = v;
    cursor[i] = v;
}

// ============================================================
// scatter into BOTH src-order and dst-order buckets
// ============================================================
__global__ __launch_bounds__(256) void scatter2_kernel(const int* __restrict__ ei,
                                                       const int* __restrict__ et,
                                                       const int* __restrict__ deg,
                                                       int* __restrict__ cursor_s,
                                                       int* __restrict__ cursor_d,
                                                       int* __restrict__ s_rel,
                                                       float* __restrict__ s_norm,
                                                       int* __restrict__ d_map,
                                                       int* __restrict__ d_pack,
                                                       float* __restrict__ d_norm) {
    int e = blockIdx.x * blockDim.x + threadIdx.x;
    if (e >= NEDGE) return;
    int src = ei[e];
    int dst = ei[NEDGE + e];
    int r   = et[e];
    float nm = 1.0f / (float)deg[dst * NREL + r];   // deg >= 1 for any present (dst,r)
    int j = atomicAdd(&cursor_s[src], 1);
    s_rel[j]  = r;
    s_norm[j] = nm;
    int k = atomicAdd(&cursor_d[dst], 1);
    d_map[k]  = j;
    d_pack[k] = src | (r << 16);
    d_norm[k] = nm;
}

// ============================================================
// layer-1 messages (src-bucketed, NO atomics):
// m1[j,h] = norm_j * sum_b comp1[r_j,b] * basis1[b,src,h]
// block = 256 (4 waves), one src per wave; basis slice staged in LDS.
// ============================================================
__global__ __launch_bounds__(256) void msg1_kernel(const float* __restrict__ basis1,
                                                   const float* __restrict__ comp1,
                                                   const int* __restrict__ offs_s,
                                                   const int* __restrict__ cnt_s,
                                                   const int* __restrict__ s_rel,
                                                   const float* __restrict__ s_norm,
                                                   float* __restrict__ m1) {
    __shared__ float bs[4 * BSTR];
    int src0 = blockIdx.x * 4;
    int t = threadIdx.x;
    // basis1[b, src0..src0+3, :] is 64 contiguous floats per b
    for (int i = t; i < NBASIS * 64; i += 256) {
        int b  = i >> 6;
        int w  = i & 63;
        int sg = w >> 4;
        int hh = w & 15;
        bs[sg * BSTR + b * HDIM + hh] = basis1[b * (NNODES * HDIM) + src0 * HDIM + w];
    }
    __syncthreads();
    int wave = t >> 6;
    int lane = t & 63;
    int src  = src0 + wave;
    int n0 = offs_s[src];
    int n1 = n0 + cnt_s[src];
    int hh = lane & (HDIM - 1);
    int g  = lane >> 4;
    const float* __restrict__ bw = bs + wave * BSTR;
    for (int j = n0 + g; j < n1; j += 4) {
        int   r  = s_rel[j];
        float nm = s_norm[j];
        const float* __restrict__ cp = comp1 + r * NBASIS;
        float acc = 0.f;
#pragma unroll
        for (int b = 0; b < NBASIS; ++b)
            acc = fmaf(cp[b], bw[b * HDIM + hh], acc);
        m1[(size_t)j * HDIM + hh] = nm * acc;
    }
}

// ============================================================
// layer-1 gather (dst-bucketed, NO atomics) + relu + root1 + bias1
// block = 256 (4 waves), one dst per wave; lane: hh = lane&15, g = lane>>4
// ============================================================
__global__ __launch_bounds__(256) void gather1_kernel(const float* __restrict__ m1,
                                                      const int* __restrict__ d_map,
                                                      const int* __restrict__ offs_d,
                                                      const int* __restrict__ cnt_d,
                                                      const float* __restrict__ root1,
                                                      const float* __restrict__ bias1,
                                                      float* __restrict__ h) {
    int t = threadIdx.x;
    int wave = t >> 6;
    int lane = t & 63;
    int dst  = blockIdx.x * 4 + wave;
    int k0 = offs_d[dst];
    int k1 = k0 + cnt_d[dst];
    int hh = lane & (HDIM - 1);
    int g  = lane >> 4;
    float acc = 0.f;
    for (int k = k0 + g; k < k1; k += 4) {
        int j = d_map[k];
        acc += m1[(size_t)j * HDIM + hh];
    }
    acc += __shfl_xor(acc, 16);
    acc += __shfl_xor(acc, 32);
    if (g == 0) {
        float v = acc + root1[dst * HDIM + hh] + bias1[hh];
        h[dst * HDIM + hh] = v > 0.f ? v : 0.f;
    }
}

// ---------------- W2[r,h,c] = sum_b comp2[r,b]*basis2[b,h,c] ----------------
__global__ __launch_bounds__(256) void w2_kernel(const float* __restrict__ basis2,
                                                 const float* __restrict__ comp2,
                                                 float* __restrict__ W2) {
    int i = blockIdx.x * blockDim.x + threadIdx.x;
    if (i >= NREL * HDIM * NCLS) return;
    int c  = i & (NCLS - 1);
    int hh = (i >> 3) & (HDIM - 1);
    int r  = i >> 7;  // H*C = 128
    float acc = 0.f;
#pragma unroll
    for (int b = 0; b < NBASIS; ++b)
        acc += comp2[r * NBASIS + b] * basis2[(b * HDIM + hh) * NCLS + c];
    W2[i] = acc;
}

// ============================================================
// layer 2 fused (dst-bucketed, NO atomics) + root2 + bias2 + log_softmax
// block = 256 (4 waves), one dst per wave; lane: c = lane&7, g = lane>>3
// ============================================================
__global__ __launch_bounds__(256) void layer2f_kernel(const float* __restrict__ h,
                                                      const float* __restrict__ W2,
                                                      const int* __restrict__ offs_d,
                                                      const int* __restrict__ cnt_d,
                                                      const int* __restrict__ d_pack,
                                                      const float* __restrict__ d_norm,
                                                      const float* __restrict__ root2,
                                                      const float* __restrict__ bias2,
                                                      float* __restrict__ out) {
    int t = threadIdx.x;
    int wave = t >> 6;
    int lane = t & 63;
    int dst  = blockIdx.x * 4 + wave;
    int k0 = offs_d[dst];
    int k1 = k0 + cnt_d[dst];
    int c = lane & (NCLS - 1);
    int g = lane >> 3;
    float acc = 0.f;
    for (int k = k0 + g; k < k1; k += 8) {
        int   pack = d_pack[k];
        int   src  = pack & 0xFFFF;
        int   r    = pack >> 16;
        float nm   = d_norm[k];
        const float* __restrict__ hv = h + src * HDIM;
        const float* __restrict__ w  = W2 + r * (HDIM * NCLS) + c;
        float a = 0.f;
#pragma unroll
        for (int kk = 0; kk < HDIM; ++kk)
            a = fmaf(hv[kk], w[kk * NCLS], a);
        acc = fmaf(nm, a, acc);
    }
    acc += __shfl_xor(acc, 8);
    acc += __shfl_xor(acc, 16);
    acc += __shfl_xor(acc, 32);
    // every lane now holds the message sum for class c of dst
    float v = acc + bias2[c];
    const float* __restrict__ hd = h + dst * HDIM;
#pragma unroll
    for (int kk = 0; kk < HDIM; ++kk)
        v = fmaf(hd[kk], root2[kk * NCLS + c], v);
    float mx = v;
    mx = fmaxf(mx, __shfl_xor(mx, 1));
    mx = fmaxf(mx, __shfl_xor(mx, 2));
    mx = fmaxf(mx, __shfl_xor(mx, 4));
    float ex = expf(v - mx);
    float s = ex;
    s += __shfl_xor(s, 1);
    s += __shfl_xor(s, 2);
    s += __shfl_xor(s, 4);
    if (g == 0) out[dst * NCLS + c] = v - mx - logf(s);
}

// ============================================================
// fallback path (round-2 bucketed, atomics; needs ~33.4 MB)
// ============================================================
__global__ __launch_bounds__(256) void layer1b_kernel(const float* __restrict__ basis1,
                                                      const float* __restrict__ comp1,
                                                      const int* __restrict__ offs,
                                                      const int* __restrict__ cnt,
                                                      const int* __restrict__ s_dst,
                                                      const int* __restrict__ s_rel,
                                                      const float* __restrict__ s_norm,
                                                      float* __restrict__ h) {
    __shared__ float bs[4 * NBASIS * HDIM];
    int src0 = blockIdx.x * 4;
    int t = threadIdx.x;
    for (int i = t; i < 4 * NBASIS * HDIM; i += 256) {
        int sg  = i / (NBASIS * HDIM);
        int rem = i - sg * (NBASIS * HDIM);
        int b   = rem >> 4;
        int hh  = rem & (HDIM - 1);
        bs[i] = basis1[b * (NNODES * HDIM) + (src0 + sg) * HDIM + hh];
    }
    __syncthreads();
    int wave = t >> 6;
    int lane = t & 63;
    int src  = src0 + wave;
    int n0 = offs[src];
    int n1 = n0 + cnt[src];
    int hh = lane & (HDIM - 1);
    int g  = lane >> 4;
    const float* __restrict__ bw = bs + wave * (NBASIS * HDIM);
    for (int j = n0 + g; j < n1; j += 4) {
        int   dst = s_dst[j];
        int   r   = s_rel[j];
        float nm  = s_norm[j];
        const float* __restrict__ cp = comp1 + r * NBASIS;
        float acc = 0.f;
#pragma unroll
        for (int b = 0; b < NBASIS; ++b)
            acc = fmaf(cp[b], bw[b * HDIM + hh], acc);
        atomicAdd(&h[dst * HDIM + hh], nm * acc);
    }
}

__global__ __launch_bounds__(256) void relu_kernel(float* __restrict__ h,
                                                   const float* __restrict__ root1,
                                                   const float* __restrict__ bias1) {
    int i = blockIdx.x * blockDim.x + threadIdx.x;
    if (i >= NNODES * HDIM) return;
    float v = h[i] + root1[i] + bias1[i & (HDIM - 1)];
    h[i] = v > 0.f ? v : 0.f;
}

__global__ __launch_bounds__(256) void layer2b_kernel(const float* __restrict__ h,
                                                      const float* __restrict__ W2,
                                                      const int* __restrict__ offs,
                                                      const int* __restrict__ cnt,
                                                      const int* __restrict__ s_dst,
                                                      const int* __restrict__ s_rel,
                                                      const float* __restrict__ s_norm,
                                                      float* __restrict__ out_tmp) {
    __shared__ float hv[4 * HDIM];
    int src0 = blockIdx.x * 4;
    int t = threadIdx.x;
    if (t < 4 * HDIM) hv[t] = h[src0 * HDIM + t];
    __syncthreads();
    int wave = t >> 6;
    int lane = t & 63;
    int src  = src0 + wave;
    int n0 = offs[src];
    int n1 = n0 + cnt[src];
    int c = lane & (NCLS - 1);
    int g = lane >> 3;
    const float* __restrict__ hw = hv + wave * HDIM;
    for (int j = n0 + g; j < n1; j += 8) {
        int   dst = s_dst[j];
        int   r   = s_rel[j];
        float nm  = s_norm[j];
        const float* __restrict__ w = W2 + r * (HDIM * NCLS) + c;
        float acc = 0.f;
#pragma unroll
        for (int k = 0; k < HDIM; ++k)
            acc = fmaf(hw[k], w[k * NCLS], acc);
        atomicAdd(&out_tmp[dst * NCLS + c], nm * acc);
    }
}

__global__ __launch_bounds__(256) void final_kernel(const float* __restrict__ out_tmp,
                                                    const float* __restrict__ h,
                                                    const float* __restrict__ root2,
                                                    const float* __restrict__ bias2,
                                                    float* __restrict__ out) {
    int n = blockIdx.x * blockDim.x + threadIdx.x;
    if (n >= NNODES) return;
    float hv[HDIM];
#pragma unroll
    for (int i = 0; i < HDIM; ++i) hv[i] = h[n * HDIM + i];
    float v[NCLS];
    float mx = -1e30f;
#pragma unroll
    for (int c = 0; c < NCLS; ++c) {
        float acc = out_tmp[n * NCLS + c] + bias2[c];
#pragma unroll
        for (int i = 0; i < HDIM; ++i) acc += hv[i] * root2[i * NCLS + c];
        v[c] = acc;
        mx = fmaxf(mx, acc);
    }
    float s = 0.f;
#pragma unroll
    for (int c = 0; c < NCLS; ++c) s += expf(v[c] - mx);
    float ls = logf(s);
#pragma unroll
    for (int c = 0; c < NCLS; ++c) out[n * NCLS + c] = v[c] - mx - ls;
}

__global__ __launch_bounds__(256) void scatter_kernel(const int* __restrict__ ei,
                                                      const int* __restrict__ et,
                                                      const int* __restrict__ deg,
                                                      int* __restrict__ cursor,
                                                      int* __restrict__ s_dst,
                                                      int* __restrict__ s_rel,
                                                      float* __restrict__ s_norm) {
    int e = blockIdx.x * blockDim.x + threadIdx.x;
    if (e >= NEDGE) return;
    int src = ei[e];
    int dst = ei[NEDGE + e];
    int r   = et[e];
    int pos = atomicAdd(&cursor[src], 1);
    s_dst[pos]  = dst;
    s_rel[pos]  = r;
    s_norm[pos] = 1.0f / (float)deg[dst * NREL + r];
}

extern "C" void kernel_launch(void* const* d_in, const int* in_sizes, int n_in,
                              void* d_out, int out_size, void* d_ws, size_t ws_size,
                              hipStream_t stream) {
    const int*   ei     = (const int*)d_in[0];
    const int*   et     = (const int*)d_in[1];
    const float* basis1 = (const float*)d_in[2];
    const float* comp1  = (const float*)d_in[3];
    const float* root1  = (const float*)d_in[4];
    const float* bias1  = (const float*)d_in[5];
    const float* basis2 = (const float*)d_in[6];
    const float* comp2  = (const float*)d_in[7];
    const float* root2  = (const float*)d_in[8];
    const float* bias2  = (const float*)d_in[9];
    float* out = (float*)d_out;

    // ---------- primary layout (words) ----------
    int*   deg      = (int*)d_ws;                                // N*R   (zero)
    int*   cnt_s    = deg + (size_t)NNODES * NREL;               // N     (zero)
    int*   cnt_d    = cnt_s + NNODES;                            // N     (zero)
    size_t zero_words = (size_t)NNODES * NREL + 2 * (size_t)NNODES;
    float* h        = (float*)(cnt_d + NNODES);                  // N*H
    float* W2       = h + (size_t)NNODES * HDIM;                 // R*H*C
    int*   offs_s   = (int*)(W2 + (size_t)NREL * HDIM * NCLS);   // N
    int*   offs_d   = offs_s + NNODES;                           // N
    int*   cursor_s = offs_d + NNODES;                           // N
    int*   cursor_d = cursor_s + NNODES;                         // N
    int*   bsum     = cursor_d + NNODES;                         // NB1
    int*   bpre     = bsum + NB1;                                // NB1
    int*   s_rel    = bpre + NB1;                                // E
    float* s_norm   = (float*)(s_rel + NEDGE);                   // E
    int*   d_map    = (int*)(s_norm + NEDGE);                    // E
    int*   d_pack   = d_map + NEDGE;                             // E
    float* d_norm   = (float*)(d_pack + NEDGE);                  // E
    float* m1       = d_norm + NEDGE;                            // E*H
    size_t total_words = zero_words + (size_t)NNODES * HDIM + (size_t)NREL * HDIM * NCLS +
                         4 * (size_t)NNODES + 2 * NB1 + 5 * (size_t)NEDGE +
                         (size_t)NEDGE * HDIM;

    if (ws_size >= total_words * sizeof(float)) {
        hipMemsetAsync(d_ws, 0, zero_words * sizeof(int), stream);
        degcnt_kernel<<<(NEDGE + 255) / 256, 256, 0, stream>>>(ei, et, deg, cnt_s, cnt_d);
        // scan src counts
        scan1_kernel<<<NB1, SCAN_B, 0, stream>>>(cnt_s, offs_s, bsum);
        scan2_kernel<<<1, SCAN_B, 0, stream>>>(bsum, bpre);
        scanadd_kernel<<<NB1, SCAN_B, 0, stream>>>(offs_s, bpre, cursor_s);
        // scan dst counts
        scan1_kernel<<<NB1, SCAN_B, 0, stream>>>(cnt_d, offs_d, bsum);
        scan2_kernel<<<1, SCAN_B, 0, stream>>>(bsum, bpre);
        scanadd_kernel<<<NB1, SCAN_B, 0, stream>>>(offs_d, bpre, cursor_d);

        scatter2_kernel<<<(NEDGE + 255) / 256, 256, 0, stream>>>(
            ei, et, deg, cursor_s, cursor_d, s_rel, s_norm, d_map, d_pack, d_norm);

        msg1_kernel<<<NNODES / 4, 256, 0, stream>>>(basis1, comp1, offs_s, cnt_s, s_rel, s_norm, m1);
        gather1_kernel<<<NNODES / 4, 256, 0, stream>>>(m1, d_map, offs_d, cnt_d, root1, bias1, h);
        w2_kernel<<<(NREL * HDIM * NCLS + 255) / 256, 256, 0, stream>>>(basis2, comp2, W2);
        layer2f_kernel<<<NNODES / 4, 256, 0, stream>>>(h, W2, offs_d, cnt_d, d_pack, d_norm,
                                                       root2, bias2, out);
        return;
    }

    // ---------- fallback: round-2 bucketed path (~33.4 MB) ----------
    {
        int*   deg_f   = (int*)d_ws;                                  // N*R
        float* h_f     = (float*)(deg_f + (size_t)NNODES * NREL);     // N*H
        float* out_tmp = h_f + (size_t)NNODES * HDIM;                 // N*C
        int*   cnt     = (int*)(out_tmp + (size_t)NNODES * NCLS);     // N
        size_t zw = (size_t)NNODES * NREL + NNODES * HDIM + NNODES * NCLS + NNODES;
        float* W2f     = (float*)(cnt + NNODES);
        int*   offs    = (int*)(W2f + (size_t)NREL * HDIM * NCLS);
        int*   cursor  = offs + NNODES;
        int*   bsum_f  = cursor + NNODES;
        int*   bpre_f  = bsum_f + NB1;
        int*   s_dst   = bpre_f + NB1;
        int*   s_rel_f = s_dst + NEDGE;
        float* s_nm_f  = (float*)(s_rel_f + NEDGE);

        hipMemsetAsync(d_ws, 0, zw * sizeof(float), stream);
        degcnt_kernel<<<(NEDGE + 255) / 256, 256, 0, stream>>>(ei, et, deg_f, cnt, cnt);
        scan1_kernel<<<NB1, SCAN_B, 0, stream>>>(cnt, offs, bsum_f);
        scan2_kernel<<<1, SCAN_B, 0, stream>>>(bsum_f, bpre_f);
        scanadd_kernel<<<NB1, SCAN_B, 0, stream>>>(offs, bpre_f, cursor);
        scatter_kernel<<<(NEDGE + 255) / 256, 256, 0, stream>>>(ei, et, deg_f, cursor,
                                                                s_dst, s_rel_f, s_nm_f);
        layer1b_kernel<<<NNODES / 4, 256, 0, stream>>>(basis1, comp1, offs, cnt,
                                                       s_dst, s_rel_f, s_nm_f, h_f);
        relu_kernel<<<(NNODES * HDIM + 255) / 256, 256, 0, stream>>>(h_f, root1, bias1);
        w2_kernel<<<(NREL * HDIM * NCLS + 255) / 256, 256, 0, stream>>>(basis2, comp2, W2f);
        layer2b_kernel<<<NNODES / 4, 256, 0, stream>>>(h_f, W2f, offs, cnt,
                                                       s_dst, s_rel_f, s_nm_f, out_tmp);
        final_kernel<<<(NNODES + 255) / 256, 256, 0, stream>>>(out_tmp, h_f, root2, bias2, out);
    }
}

// Round 4
// 344.808 us; speedup vs baseline: 1.1615x; 1.1615x over previous
//
#include <hip/hip_runtime.h>

#define NNODES 50000
#define NREL   90
#define NEDGE  800000
#define HDIM   16
#define NBASIS 30
#define NCLS   8
#define SCAN_B 256
#define NB1    ((NNODES + SCAN_B - 1) / SCAN_B)   // 196

// ============================================================
// histogram: deg[dst*R+r]++, cnt_s[src]++, cnt_d[dst]++
// ============================================================
__global__ __launch_bounds__(256) void degcnt_kernel(const int* __restrict__ ei,
                                                     const int* __restrict__ et,
                                                     int* __restrict__ deg,
                                                     int* __restrict__ cnt_s,
                                                     int* __restrict__ cnt_d) {
    int e = blockIdx.x * blockDim.x + threadIdx.x;
    if (e >= NEDGE) return;
    int src = ei[e];
    int dst = ei[NEDGE + e];
    int r   = et[e];
    atomicAdd(&deg[dst * NREL + r], 1);
    atomicAdd(&cnt_s[src], 1);
    atomicAdd(&cnt_d[dst], 1);
}

// ---------------- 2-level exclusive scan over NNODES ----------------
__global__ __launch_bounds__(SCAN_B) void scan1_kernel(const int* __restrict__ cnt,
                                                       int* __restrict__ offs,
                                                       int* __restrict__ bsum) {
    __shared__ int tmp[SCAN_B];
    int gid = blockIdx.x * SCAN_B + threadIdx.x;
    int v = (gid < NNODES) ? cnt[gid] : 0;
    tmp[threadIdx.x] = v;
    for (int d = 1; d < SCAN_B; d <<= 1) {
        __syncthreads();
        int t = (threadIdx.x >= d) ? tmp[threadIdx.x - d] : 0;
        __syncthreads();
        tmp[threadIdx.x] += t;
    }
    __syncthreads();
    if (gid < NNODES) offs[gid] = tmp[threadIdx.x] - v;
    if (threadIdx.x == SCAN_B - 1) bsum[blockIdx.x] = tmp[SCAN_B - 1];
}

__global__ __launch_bounds__(SCAN_B) void scan2_kernel(const int* __restrict__ bsum,
                                                       int* __restrict__ bpre) {
    __shared__ int tmp[SCAN_B];
    int v = (threadIdx.x < NB1) ? bsum[threadIdx.x] : 0;
    tmp[threadIdx.x] = v;
    for (int d = 1; d < SCAN_B; d <<= 1) {
        __syncthreads();
        int t = (threadIdx.x >= d) ? tmp[threadIdx.x - d] : 0;
        __syncthreads();
        tmp[threadIdx.x] += t;
    }
    __syncthreads();
    if (threadIdx.x < NB1) bpre[threadIdx.x] = tmp[threadIdx.x] - v;
}

__global__ __launch_bounds__(SCAN_B) void scanadd_kernel(int* __restrict__ offs,
                                                         const int* __restrict__ bpre,
                                                         int* __restrict__ cursor) {
    int i = blockIdx.x * SCAN_B + threadIdx.x;
    if (i >= NNODES) return;
    int v = offs[i] + bpre[i >> 8];
    offs[i] = v;
    cursor[i] = v;
}

// ============================================================
// scatter: src-ordered records {src|rel, norm, dst-slot k}; dst-ordered {src|rel, norm}
// ============================================================
__global__ __launch_bounds__(256) void scatter2_kernel(const int* __restrict__ ei,
                                                       const int* __restrict__ et,
                                                       const int* __restrict__ deg,
                                                       int* __restrict__ cur_s,
                                                       int* __restrict__ cur_d,
                                                       int* __restrict__ s_sr,
                                                       float* __restrict__ s_norm,
                                                       int* __restrict__ s_k,
                                                       int* __restrict__ d_pack,
                                                       float* __restrict__ d_norm) {
    int e = blockIdx.x * blockDim.x + threadIdx.x;
    if (e >= NEDGE) return;
    int src = ei[e];
    int dst = ei[NEDGE + e];
    int r   = et[e];
    float nm = 1.0f / (float)deg[dst * NREL + r];   // deg >= 1 for present (dst,r)
    int pk = src | (r << 16);                        // src < 65536, r < 90
    int j = atomicAdd(&cur_s[src], 1);
    int k = atomicAdd(&cur_d[dst], 1);
    s_sr[j]   = pk;
    s_norm[j] = nm;
    s_k[j]    = k;
    d_pack[k] = pk;
    d_norm[k] = nm;
}

// ============================================================
// layer-1 messages, flat: thread per (edge, h-quad). Edges src-sorted ->
// basis1 lines are L1/L2-hot. Stores m1 directly at dst-slot k (full 64B lines).
// ============================================================
__global__ __launch_bounds__(256) void msg1_flat(const float* __restrict__ basis1,
                                                 const float* __restrict__ comp1,
                                                 const int* __restrict__ s_sr,
                                                 const float* __restrict__ s_norm,
                                                 const int* __restrict__ s_k,
                                                 float* __restrict__ m1d) {
    int idx = blockIdx.x * blockDim.x + threadIdx.x;   // NEDGE*4 = 3,200,000 exact
    int j = idx >> 2;
    int q = idx & 3;
    int pk  = s_sr[j];
    int src = pk & 0xFFFF;
    int r   = pk >> 16;
    const float* __restrict__ cp = comp1 + r * NBASIS;
    const float4* __restrict__ bp = (const float4*)basis1 + (size_t)src * 4 + q;
    float4 acc = make_float4(0.f, 0.f, 0.f, 0.f);
#pragma unroll
    for (int b = 0; b < NBASIS; ++b) {
        float4 bv = bp[(size_t)b * (NNODES * 4)];
        float  cb = cp[b];
        acc.x = fmaf(cb, bv.x, acc.x);
        acc.y = fmaf(cb, bv.y, acc.y);
        acc.z = fmaf(cb, bv.z, acc.z);
        acc.w = fmaf(cb, bv.w, acc.w);
    }
    float nm = s_norm[j];
    int   k  = s_k[j];
    ((float4*)m1d)[(size_t)k * 4 + q] =
        make_float4(nm * acc.x, nm * acc.y, nm * acc.z, nm * acc.w);
}

// ============================================================
// layer-1 gather, flat: thread per (dst, h-quad); m1 is dst-sorted -> sequential.
// Fuses root1 + bias1 + relu.
// ============================================================
__global__ __launch_bounds__(256) void gather1_flat(const float* __restrict__ m1d,
                                                    const int* __restrict__ offs_d,
                                                    const int* __restrict__ cnt_d,
                                                    const float* __restrict__ root1,
                                                    const float* __restrict__ bias1,
                                                    float* __restrict__ h) {
    int idx = blockIdx.x * blockDim.x + threadIdx.x;
    if (idx >= NNODES * 4) return;
    int dst = idx >> 2;
    int q   = idx & 3;
    int k0 = offs_d[dst];
    int k1 = k0 + cnt_d[dst];
    const float4* __restrict__ mp = (const float4*)m1d + q;
    float4 acc = make_float4(0.f, 0.f, 0.f, 0.f);
    for (int k = k0; k < k1; ++k) {
        float4 v = mp[(size_t)k * 4];
        acc.x += v.x; acc.y += v.y; acc.z += v.z; acc.w += v.w;
    }
    float4 rt = ((const float4*)root1)[idx];
    float4 bi = ((const float4*)bias1)[q];
    float4 o;
    o.x = fmaxf(acc.x + rt.x + bi.x, 0.f);
    o.y = fmaxf(acc.y + rt.y + bi.y, 0.f);
    o.z = fmaxf(acc.z + rt.z + bi.z, 0.f);
    o.w = fmaxf(acc.w + rt.w + bi.w, 0.f);
    ((float4*)h)[idx] = o;
}

// ============================================================
// W2 transposed: w2t[r][c][hh] ; r2t[c][hh] = root2[hh][c]
// ============================================================
__global__ __launch_bounds__(256) void w2_kernel(const float* __restrict__ basis2,
                                                 const float* __restrict__ comp2,
                                                 const float* __restrict__ root2,
                                                 float* __restrict__ w2t,
                                                 float* __restrict__ r2t) {
    int i = blockIdx.x * blockDim.x + threadIdx.x;
    if (i >= NREL * HDIM * NCLS) return;
    int kk = i & (HDIM - 1);
    int c  = (i >> 4) & (NCLS - 1);
    int r  = i >> 7;
    float acc = 0.f;
#pragma unroll
    for (int b = 0; b < NBASIS; ++b)
        acc += comp2[r * NBASIS + b] * basis2[(b * HDIM + kk) * NCLS + c];
    w2t[i] = acc;
    if (i < HDIM * NCLS) {
        int c2 = i >> 4;
        int k2 = i & (HDIM - 1);
        r2t[i] = root2[k2 * NCLS + c2];
    }
}

// ============================================================
// layer 2 fused, flat: thread per (dst, c); dst-sorted edge records sequential.
// float4 dots against transposed W2; fused root2 + bias2 + log_softmax (8-lane shfl).
// ============================================================
__global__ __launch_bounds__(256) void layer2f_flat(const float* __restrict__ h,
                                                    const float* __restrict__ w2t,
                                                    const float* __restrict__ r2t,
                                                    const int* __restrict__ offs_d,
                                                    const int* __restrict__ cnt_d,
                                                    const int* __restrict__ d_pack,
                                                    const float* __restrict__ d_norm,
                                                    const float* __restrict__ bias2,
                                                    float* __restrict__ out) {
    int idx = blockIdx.x * blockDim.x + threadIdx.x;
    if (idx >= NNODES * NCLS) return;   // tail = whole 8-groups (400000 % 8 == 0)
    int dst = idx >> 3;
    int c   = idx & (NCLS - 1);
    int k0 = offs_d[dst];
    int k1 = k0 + cnt_d[dst];
    const float4* __restrict__ h4 = (const float4*)h;
    const float4* __restrict__ w4 = (const float4*)w2t;
    float acc = 0.f;
    for (int k = k0; k < k1; ++k) {
        int   pk = d_pack[k];
        float nm = d_norm[k];
        int src = pk & 0xFFFF;
        int r   = pk >> 16;
        const float4* __restrict__ hp = h4 + src * 4;
        const float4* __restrict__ wp = w4 + (r * NCLS + c) * 4;
        float a = 0.f;
#pragma unroll
        for (int qq = 0; qq < 4; ++qq) {
            float4 hv = hp[qq];
            float4 wv = wp[qq];
            a = fmaf(hv.x, wv.x, a);
            a = fmaf(hv.y, wv.y, a);
            a = fmaf(hv.z, wv.z, a);
            a = fmaf(hv.w, wv.w, a);
        }
        acc = fmaf(nm, a, acc);
    }
    float v = acc + bias2[c];
    const float4* __restrict__ hd = h4 + dst * 4;
    const float4* __restrict__ rp = (const float4*)r2t + c * 4;
#pragma unroll
    for (int qq = 0; qq < 4; ++qq) {
        float4 hv = hd[qq];
        float4 rv = rp[qq];
        v = fmaf(hv.x, rv.x, v);
        v = fmaf(hv.y, rv.y, v);
        v = fmaf(hv.z, rv.z, v);
        v = fmaf(hv.w, rv.w, v);
    }
    float mx = v;
    mx = fmaxf(mx, __shfl_xor(mx, 1));
    mx = fmaxf(mx, __shfl_xor(mx, 2));
    mx = fmaxf(mx, __shfl_xor(mx, 4));
    float s = expf(v - mx);
    s += __shfl_xor(s, 1);
    s += __shfl_xor(s, 2);
    s += __shfl_xor(s, 4);
    out[idx] = v - mx - logf(s);
}

// ============================================================
// fallback (round-1 flat path + transposed W2; needs ~23.3 MB)
// ============================================================
__global__ __launch_bounds__(256) void layer1_flat(const int* __restrict__ ei,
                                                   const int* __restrict__ et,
                                                   const float* __restrict__ basis1,
                                                   const float* __restrict__ comp1,
                                                   const int* __restrict__ deg,
                                                   float* __restrict__ h) {
    long long idx = (long long)blockIdx.x * blockDim.x + threadIdx.x;
    if (idx >= (long long)NEDGE * HDIM) return;
    int e  = (int)(idx >> 4);
    int hh = (int)(idx & (HDIM - 1));
    int src = ei[e];
    int dst = ei[NEDGE + e];
    int r   = et[e];
    float norm = 1.0f / (float)deg[dst * NREL + r];
    const float* __restrict__ cp = comp1 + r * NBASIS;
    float acc = 0.f;
#pragma unroll
    for (int b = 0; b < NBASIS; ++b)
        acc += cp[b] * basis1[(b * NNODES + src) * HDIM + hh];
    atomicAdd(&h[dst * HDIM + hh], norm * acc);
}

__global__ __launch_bounds__(256) void relu_kernel(float* __restrict__ h,
                                                   const float* __restrict__ root1,
                                                   const float* __restrict__ bias1) {
    int i = blockIdx.x * blockDim.x + threadIdx.x;
    if (i >= NNODES * HDIM) return;
    float v = h[i] + root1[i] + bias1[i & (HDIM - 1)];
    h[i] = v > 0.f ? v : 0.f;
}

__global__ __launch_bounds__(256) void layer2_flat(const int* __restrict__ ei,
                                                   const int* __restrict__ et,
                                                   const float* __restrict__ h,
                                                   const float* __restrict__ w2t,
                                                   const int* __restrict__ deg,
                                                   float* __restrict__ out_tmp) {
    long long idx = (long long)blockIdx.x * blockDim.x + threadIdx.x;
    if (idx >= (long long)NEDGE * NCLS) return;
    int e = (int)(idx >> 3);
    int c = (int)(idx & (NCLS - 1));
    int src = ei[e];
    int dst = ei[NEDGE + e];
    int r   = et[e];
    float norm = 1.0f / (float)deg[dst * NREL + r];
    const float4* __restrict__ hp = (const float4*)h + src * 4;
    const float4* __restrict__ wp = (const float4*)w2t + (r * NCLS + c) * 4;
    float a = 0.f;
#pragma unroll
    for (int qq = 0; qq < 4; ++qq) {
        float4 hv = hp[qq];
        float4 wv = wp[qq];
        a = fmaf(hv.x, wv.x, a);
        a = fmaf(hv.y, wv.y, a);
        a = fmaf(hv.z, wv.z, a);
        a = fmaf(hv.w, wv.w, a);
    }
    atomicAdd(&out_tmp[dst * NCLS + c], norm * a);
}

__global__ __launch_bounds__(256) void final_kernel(const float* __restrict__ out_tmp,
                                                    const float* __restrict__ h,
                                                    const float* __restrict__ root2,
                                                    const float* __restrict__ bias2,
                                                    float* __restrict__ out) {
    int n = blockIdx.x * blockDim.x + threadIdx.x;
    if (n >= NNODES) return;
    float hv[HDIM];
#pragma unroll
    for (int i = 0; i < HDIM; ++i) hv[i] = h[n * HDIM + i];
    float v[NCLS];
    float mx = -1e30f;
#pragma unroll
    for (int c = 0; c < NCLS; ++c) {
        float acc = out_tmp[n * NCLS + c] + bias2[c];
#pragma unroll
        for (int i = 0; i < HDIM; ++i) acc += hv[i] * root2[i * NCLS + c];
        v[c] = acc;
        mx = fmaxf(mx, acc);
    }
    float s = 0.f;
#pragma unroll
    for (int c = 0; c < NCLS; ++c) s += expf(v[c] - mx);
    float ls = logf(s);
#pragma unroll
    for (int c = 0; c < NCLS; ++c) out[n * NCLS + c] = v[c] - mx - ls;
}

extern "C" void kernel_launch(void* const* d_in, const int* in_sizes, int n_in,
                              void* d_out, int out_size, void* d_ws, size_t ws_size,
                              hipStream_t stream) {
    const int*   ei     = (const int*)d_in[0];
    const int*   et     = (const int*)d_in[1];
    const float* basis1 = (const float*)d_in[2];
    const float* comp1  = (const float*)d_in[3];
    const float* root1  = (const float*)d_in[4];
    const float* bias1  = (const float*)d_in[5];
    const float* basis2 = (const float*)d_in[6];
    const float* comp2  = (const float*)d_in[7];
    const float* root2  = (const float*)d_in[8];
    const float* bias2  = (const float*)d_in[9];
    float* out = (float*)d_out;

    // ---------- primary layout (4-byte words) ----------
    int*   deg    = (int*)d_ws;                         // N*R    (zero)
    int*   cnt_s  = deg + (size_t)NNODES * NREL;        // N      (zero)
    int*   cnt_d  = cnt_s + NNODES;                     // N      (zero)
    size_t zero_words = (size_t)NNODES * NREL + 2 * (size_t)NNODES;
    int*   offs_s = cnt_d + NNODES;                     // N
    int*   offs_d = offs_s + NNODES;                    // N
    int*   cur_s  = offs_d + NNODES;                    // N
    int*   cur_d  = cur_s + NNODES;                     // N
    int*   bsum   = cur_d + NNODES;                     // NB1
    int*   bpre   = bsum + NB1;                         // NB1
    int*   s_sr   = bpre + NB1;                         // E
    float* s_norm = (float*)(s_sr + NEDGE);             // E
    int*   s_k    = (int*)(s_norm + NEDGE);             // E
    int*   d_pack = s_k + NEDGE;                        // E
    float* d_norm = (float*)(d_pack + NEDGE);           // E
    float* m1d    = d_norm + NEDGE;                     // E*H  (16B-aligned: offset%4==0)
    float* h      = m1d + (size_t)NEDGE * HDIM;         // N*H
    float* w2t    = h + (size_t)NNODES * HDIM;          // R*H*C
    float* r2t    = w2t + (size_t)NREL * HDIM * NCLS;   // H*C
    size_t total_words = zero_words + 4 * (size_t)NNODES + 2 * NB1 + 5 * (size_t)NEDGE +
                         (size_t)NEDGE * HDIM + (size_t)NNODES * HDIM +
                         (size_t)NREL * HDIM * NCLS + HDIM * NCLS;

    if (ws_size >= total_words * sizeof(float)) {
        hipMemsetAsync(d_ws, 0, zero_words * sizeof(int), stream);
        degcnt_kernel<<<(NEDGE + 255) / 256, 256, 0, stream>>>(ei, et, deg, cnt_s, cnt_d);
        scan1_kernel<<<NB1, SCAN_B, 0, stream>>>(cnt_s, offs_s, bsum);
        scan2_kernel<<<1, SCAN_B, 0, stream>>>(bsum, bpre);
        scanadd_kernel<<<NB1, SCAN_B, 0, stream>>>(offs_s, bpre, cur_s);
        scan1_kernel<<<NB1, SCAN_B, 0, stream>>>(cnt_d, offs_d, bsum);
        scan2_kernel<<<1, SCAN_B, 0, stream>>>(bsum, bpre);
        scanadd_kernel<<<NB1, SCAN_B, 0, stream>>>(offs_d, bpre, cur_d);
        scatter2_kernel<<<(NEDGE + 255) / 256, 256, 0, stream>>>(
            ei, et, deg, cur_s, cur_d, s_sr, s_norm, s_k, d_pack, d_norm);

        msg1_flat<<<(NEDGE * 4) / 256, 256, 0, stream>>>(basis1, comp1, s_sr, s_norm, s_k, m1d);
        gather1_flat<<<(NNODES * 4 + 255) / 256, 256, 0, stream>>>(m1d, offs_d, cnt_d,
                                                                   root1, bias1, h);
        w2_kernel<<<(NREL * HDIM * NCLS + 255) / 256, 256, 0, stream>>>(basis2, comp2, root2,
                                                                        w2t, r2t);
        layer2f_flat<<<(NNODES * NCLS + 255) / 256, 256, 0, stream>>>(
            h, w2t, r2t, offs_d, cnt_d, d_pack, d_norm, bias2, out);
        return;
    }

    // ---------- fallback: flat atomic path (~23.3 MB) ----------
    {
        int*   deg_f   = (int*)d_ws;                               // N*R  (zero)
        float* h_f     = (float*)(deg_f + (size_t)NNODES * NREL);  // N*H  (zero)
        float* out_tmp = h_f + (size_t)NNODES * HDIM;              // N*C  (zero)
        size_t zw = (size_t)NNODES * NREL + NNODES * HDIM + NNODES * NCLS;
        float* w2t_f   = out_tmp + (size_t)NNODES * NCLS;          // R*H*C
        float* r2t_f   = w2t_f + (size_t)NREL * HDIM * NCLS;       // H*C (unused)
        int*   cnt_a   = (int*)(r2t_f + HDIM * NCLS);              // N (dummy)

        hipMemsetAsync(d_ws, 0, (zw + NNODES) * sizeof(float), stream);
        degcnt_kernel<<<(NEDGE + 255) / 256, 256, 0, stream>>>(ei, et, deg_f, cnt_a, cnt_a);
        layer1_flat<<<((size_t)NEDGE * HDIM + 255) / 256, 256, 0, stream>>>(
            ei, et, basis1, comp1, deg_f, h_f);
        relu_kernel<<<(NNODES * HDIM + 255) / 256, 256, 0, stream>>>(h_f, root1, bias1);
        w2_kernel<<<(NREL * HDIM * NCLS + 255) / 256, 256, 0, stream>>>(basis2, comp2, root2,
                                                                        w2t_f, r2t_f);
        layer2_flat<<<((size_t)NEDGE * NCLS + 255) / 256, 256, 0, stream>>>(
            ei, et, h_f, w2t_f, deg_f, out_tmp);
        final_kernel<<<(NNODES + 255) / 256, 256, 0, stream>>>(out_tmp, h_f, root2, bias2, out);
    }
}

// Round 5
// 343.647 us; speedup vs baseline: 1.1654x; 1.0034x over previous
//
#include <hip/hip_runtime.h>

#define NNODES 50000
#define NREL   90
#define NEDGE  800000
#define HDIM   16
#define NBASIS 30
#define NCLS   8
#define SCAN_B 256
#define NB1    ((NNODES + SCAN_B - 1) / SCAN_B)   // 196
#define GS     8      // srcs per msg1 block
#define BSTR   484    // padded per-src slice stride in floats (480 + 4)

// ============================================================
// histogram: cnt_s[src]++, cnt_d[dst]++   (deg histogram eliminated)
// ============================================================
__global__ __launch_bounds__(256) void cnt_kernel(const int* __restrict__ ei,
                                                  int* __restrict__ cnt_s,
                                                  int* __restrict__ cnt_d) {
    int e = blockIdx.x * blockDim.x + threadIdx.x;
    if (e >= NEDGE) return;
    atomicAdd(&cnt_s[ei[e]], 1);
    atomicAdd(&cnt_d[ei[NEDGE + e]], 1);
}

// ---------------- batched 2-level exclusive scan (src + dst in one launch) ----------------
__global__ __launch_bounds__(SCAN_B) void scan1_batch(const int* __restrict__ cnt_s,
                                                      const int* __restrict__ cnt_d,
                                                      int* __restrict__ offs_s,
                                                      int* __restrict__ offs_d,
                                                      int* __restrict__ bsum_s,
                                                      int* __restrict__ bsum_d) {
    __shared__ int tmp[SCAN_B];
    int which = blockIdx.x / NB1;
    int bid   = blockIdx.x - which * NB1;
    const int* cnt = which ? cnt_d : cnt_s;
    int* offs = which ? offs_d : offs_s;
    int* bsum = which ? bsum_d : bsum_s;
    int gid = bid * SCAN_B + threadIdx.x;
    int v = (gid < NNODES) ? cnt[gid] : 0;
    tmp[threadIdx.x] = v;
    for (int d = 1; d < SCAN_B; d <<= 1) {
        __syncthreads();
        int t = (threadIdx.x >= d) ? tmp[threadIdx.x - d] : 0;
        __syncthreads();
        tmp[threadIdx.x] += t;
    }
    __syncthreads();
    if (gid < NNODES) offs[gid] = tmp[threadIdx.x] - v;
    if (threadIdx.x == SCAN_B - 1) bsum[bid] = tmp[SCAN_B - 1];
}

__global__ __launch_bounds__(SCAN_B) void scan2_batch(const int* __restrict__ bsum_s,
                                                      const int* __restrict__ bsum_d,
                                                      int* __restrict__ bpre_s,
                                                      int* __restrict__ bpre_d) {
    __shared__ int tmp[SCAN_B];
    const int* bsum = blockIdx.x ? bsum_d : bsum_s;
    int* bpre = blockIdx.x ? bpre_d : bpre_s;
    int v = (threadIdx.x < NB1) ? bsum[threadIdx.x] : 0;
    tmp[threadIdx.x] = v;
    for (int d = 1; d < SCAN_B; d <<= 1) {
        __syncthreads();
        int t = (threadIdx.x >= d) ? tmp[threadIdx.x - d] : 0;
        __syncthreads();
        tmp[threadIdx.x] += t;
    }
    __syncthreads();
    if (threadIdx.x < NB1) bpre[threadIdx.x] = tmp[threadIdx.x] - v;
}

__global__ __launch_bounds__(SCAN_B) void scanadd_batch(int* __restrict__ offs_s,
                                                        int* __restrict__ offs_d,
                                                        const int* __restrict__ bpre_s,
                                                        const int* __restrict__ bpre_d,
                                                        int* __restrict__ cur_s,
                                                        int* __restrict__ cur_d) {
    int which = blockIdx.x / NB1;
    int bid   = blockIdx.x - which * NB1;
    int i = bid * SCAN_B + threadIdx.x;
    if (i >= NNODES) return;
    int* offs = which ? offs_d : offs_s;
    const int* bpre = which ? bpre_d : bpre_s;
    int* cur = which ? cur_d : cur_s;
    int v = offs[i] + bpre[bid];
    offs[i] = v;
    cur[i] = v;
}

// ============================================================
// scatter: src-ordered rec {pk, dst-slot k}; dst-ordered rec {pk, dst}
// pk = src | (r<<16)
// ============================================================
__global__ __launch_bounds__(256) void scatter2_kernel(const int* __restrict__ ei,
                                                       const int* __restrict__ et,
                                                       int* __restrict__ cur_s,
                                                       int* __restrict__ cur_d,
                                                       int2* __restrict__ s_rec,
                                                       int2* __restrict__ d_rec) {
    int e = blockIdx.x * blockDim.x + threadIdx.x;
    if (e >= NEDGE) return;
    int src = ei[e];
    int dst = ei[NEDGE + e];
    int r   = et[e];
    int pk = src | (r << 16);
    int j = atomicAdd(&cur_s[src], 1);
    int k = atomicAdd(&cur_d[dst], 1);
    s_rec[j] = make_int2(pk, k);
    d_rec[k] = make_int2(pk, dst);
}

// ============================================================
// per-edge norm: 1 / #{edges in dst-bucket with same relation}
// ============================================================
__global__ __launch_bounds__(256) void norm_kernel(const int2* __restrict__ d_rec,
                                                   const int* __restrict__ offs_d,
                                                   const int* __restrict__ cnt_d,
                                                   float* __restrict__ d_norm) {
    int k = blockIdx.x * blockDim.x + threadIdx.x;
    if (k >= NEDGE) return;
    int2 rec = d_rec[k];
    int dst = rec.y;
    int r   = rec.x >> 16;
    int k0 = offs_d[dst];
    int k1 = k0 + cnt_d[dst];
    int c = 0;
    for (int kk = k0; kk < k1; ++kk)
        c += ((d_rec[kk].x >> 16) == r);
    d_norm[k] = 1.0f / (float)c;
}

// ============================================================
// layer-1 messages: block stages basis1 slices of GS=8 consecutive srcs in LDS
// (fill is a pure 512B-contiguous stream per b) + comp1 in LDS, then processes
// all edges of those srcs flat: work item = (edge, h-quad).
// Stores UNNORMALIZED message direct to dst-slot k.
// ============================================================
__global__ __launch_bounds__(256) void msg1_lds(const float* __restrict__ basis1,
                                                const float* __restrict__ comp1,
                                                const int* __restrict__ offs_s,
                                                const int* __restrict__ cnt_s,
                                                const int2* __restrict__ s_rec,
                                                float* __restrict__ m1d) {
    __shared__ float bs[GS * BSTR];          // 8 slices, padded
    __shared__ float cs[NREL * NBASIS];      // comp1, 10.8 KB
    int src0 = blockIdx.x * GS;
    int t = threadIdx.x;
    // fill comp1: 2700 floats = 675 float4
    for (int i = t; i < (NREL * NBASIS) / 4; i += 256)
        ((float4*)cs)[i] = ((const float4*)comp1)[i];
    // fill basis slices: per b, 8 srcs x 16 floats = 512B contiguous
    for (int i4 = t; i4 < NBASIS * 32; i4 += 256) {   // 960 float4s
        int b = i4 >> 5;
        int w = i4 & 31;          // float4 index within the 128-float row chunk
        float4 v = ((const float4*)basis1)[(size_t)b * (NNODES * 4) + (size_t)src0 * 4 + w];
        int s = w >> 2;
        int q = w & 3;
        *((float4*)(bs + s * BSTR + b * HDIM) + q) = v;
    }
    __syncthreads();

    int n0 = offs_s[src0];
    int lastS = src0 + GS - 1;
    int n1 = offs_s[lastS] + cnt_s[lastS];
    for (int ii = n0 * 4 + t; ii < n1 * 4; ii += 256) {
        int j = ii >> 2;
        int q = ii & 3;
        int2 rec = s_rec[j];
        int src = rec.x & 0xFFFF;
        int r   = rec.x >> 16;
        const float* __restrict__ bw = bs + (src - src0) * BSTR + q * 4;
        const float* __restrict__ cp = cs + r * NBASIS;
        float4 acc = make_float4(0.f, 0.f, 0.f, 0.f);
#pragma unroll
        for (int b = 0; b < NBASIS; ++b) {
            float4 bv = *(const float4*)(bw + b * HDIM);
            float  cb = cp[b];
            acc.x = fmaf(cb, bv.x, acc.x);
            acc.y = fmaf(cb, bv.y, acc.y);
            acc.z = fmaf(cb, bv.z, acc.z);
            acc.w = fmaf(cb, bv.w, acc.w);
        }
        ((float4*)m1d)[(size_t)rec.y * 4 + q] = acc;
    }
}

// ============================================================
// layer-1 gather: thread per (dst, h-quad); m1 dst-sorted -> sequential reads.
// Applies per-edge norm here; fuses root1 + bias1 + relu.
// ============================================================
__global__ __launch_bounds__(256) void gather1_flat(const float* __restrict__ m1d,
                                                    const float* __restrict__ d_norm,
                                                    const int* __restrict__ offs_d,
                                                    const int* __restrict__ cnt_d,
                                                    const float* __restrict__ root1,
                                                    const float* __restrict__ bias1,
                                                    float* __restrict__ h) {
    int idx = blockIdx.x * blockDim.x + threadIdx.x;
    if (idx >= NNODES * 4) return;
    int dst = idx >> 2;
    int q   = idx & 3;
    int k0 = offs_d[dst];
    int k1 = k0 + cnt_d[dst];
    const float4* __restrict__ mp = (const float4*)m1d + q;
    float4 acc = make_float4(0.f, 0.f, 0.f, 0.f);
    for (int k = k0; k < k1; ++k) {
        float4 v = mp[(size_t)k * 4];
        float nm = d_norm[k];
        acc.x = fmaf(nm, v.x, acc.x);
        acc.y = fmaf(nm, v.y, acc.y);
        acc.z = fmaf(nm, v.z, acc.z);
        acc.w = fmaf(nm, v.w, acc.w);
    }
    float4 rt = ((const float4*)root1)[idx];
    float4 bi = ((const float4*)bias1)[q];
    float4 o;
    o.x = fmaxf(acc.x + rt.x + bi.x, 0.f);
    o.y = fmaxf(acc.y + rt.y + bi.y, 0.f);
    o.z = fmaxf(acc.z + rt.z + bi.z, 0.f);
    o.w = fmaxf(acc.w + rt.w + bi.w, 0.f);
    ((float4*)h)[idx] = o;
}

// ============================================================
// W2 transposed: w2t[r][c][hh] ; r2t[c][hh] = root2[hh][c]
// ============================================================
__global__ __launch_bounds__(256) void w2_kernel(const float* __restrict__ basis2,
                                                 const float* __restrict__ comp2,
                                                 const float* __restrict__ root2,
                                                 float* __restrict__ w2t,
                                                 float* __restrict__ r2t) {
    int i = blockIdx.x * blockDim.x + threadIdx.x;
    if (i >= NREL * HDIM * NCLS) return;
    int kk = i & (HDIM - 1);
    int c  = (i >> 4) & (NCLS - 1);
    int r  = i >> 7;
    float acc = 0.f;
#pragma unroll
    for (int b = 0; b < NBASIS; ++b)
        acc += comp2[r * NBASIS + b] * basis2[(b * HDIM + kk) * NCLS + c];
    w2t[i] = acc;
    if (i < HDIM * NCLS) {
        int c2 = i >> 4;
        int k2 = i & (HDIM - 1);
        r2t[i] = root2[k2 * NCLS + c2];
    }
}

// ============================================================
// layer 2 fused: thread per (dst, c); dst-sorted records sequential.
// fused root2 + bias2 + log_softmax (8-lane shfl).
// ============================================================
__global__ __launch_bounds__(256) void layer2f_flat(const float* __restrict__ h,
                                                    const float* __restrict__ w2t,
                                                    const float* __restrict__ r2t,
                                                    const int* __restrict__ offs_d,
                                                    const int* __restrict__ cnt_d,
                                                    const int2* __restrict__ d_rec,
                                                    const float* __restrict__ d_norm,
                                                    const float* __restrict__ bias2,
                                                    float* __restrict__ out) {
    int idx = blockIdx.x * blockDim.x + threadIdx.x;
    if (idx >= NNODES * NCLS) return;
    int dst = idx >> 3;
    int c   = idx & (NCLS - 1);
    int k0 = offs_d[dst];
    int k1 = k0 + cnt_d[dst];
    const float4* __restrict__ h4 = (const float4*)h;
    const float4* __restrict__ w4 = (const float4*)w2t;
    float acc = 0.f;
    for (int k = k0; k < k1; ++k) {
        int2  rec = d_rec[k];
        float nm  = d_norm[k];
        int src = rec.x & 0xFFFF;
        int r   = rec.x >> 16;
        const float4* __restrict__ hp = h4 + src * 4;
        const float4* __restrict__ wp = w4 + (r * NCLS + c) * 4;
        float a = 0.f;
#pragma unroll
        for (int qq = 0; qq < 4; ++qq) {
            float4 hv = hp[qq];
            float4 wv = wp[qq];
            a = fmaf(hv.x, wv.x, a);
            a = fmaf(hv.y, wv.y, a);
            a = fmaf(hv.z, wv.z, a);
            a = fmaf(hv.w, wv.w, a);
        }
        acc = fmaf(nm, a, acc);
    }
    float v = acc + bias2[c];
    const float4* __restrict__ hd = h4 + dst * 4;
    const float4* __restrict__ rp = (const float4*)r2t + c * 4;
#pragma unroll
    for (int qq = 0; qq < 4; ++qq) {
        float4 hv = hd[qq];
        float4 rv = rp[qq];
        v = fmaf(hv.x, rv.x, v);
        v = fmaf(hv.y, rv.y, v);
        v = fmaf(hv.z, rv.z, v);
        v = fmaf(hv.w, rv.w, v);
    }
    float mx = v;
    mx = fmaxf(mx, __shfl_xor(mx, 1));
    mx = fmaxf(mx, __shfl_xor(mx, 2));
    mx = fmaxf(mx, __shfl_xor(mx, 4));
    float s = expf(v - mx);
    s += __shfl_xor(s, 1);
    s += __shfl_xor(s, 2);
    s += __shfl_xor(s, 4);
    out[idx] = v - mx - logf(s);
}

// ============================================================
// fallback (flat atomic path; needs ~23.3 MB)
// ============================================================
__global__ __launch_bounds__(256) void degcnt_fb(const int* __restrict__ ei,
                                                 const int* __restrict__ et,
                                                 int* __restrict__ deg) {
    int e = blockIdx.x * blockDim.x + threadIdx.x;
    if (e >= NEDGE) return;
    atomicAdd(&deg[ei[NEDGE + e] * NREL + et[e]], 1);
}

__global__ __launch_bounds__(256) void layer1_flat(const int* __restrict__ ei,
                                                   const int* __restrict__ et,
                                                   const float* __restrict__ basis1,
                                                   const float* __restrict__ comp1,
                                                   const int* __restrict__ deg,
                                                   float* __restrict__ h) {
    long long idx = (long long)blockIdx.x * blockDim.x + threadIdx.x;
    if (idx >= (long long)NEDGE * HDIM) return;
    int e  = (int)(idx >> 4);
    int hh = (int)(idx & (HDIM - 1));
    int src = ei[e];
    int dst = ei[NEDGE + e];
    int r   = et[e];
    float norm = 1.0f / (float)deg[dst * NREL + r];
    const float* __restrict__ cp = comp1 + r * NBASIS;
    float acc = 0.f;
#pragma unroll
    for (int b = 0; b < NBASIS; ++b)
        acc += cp[b] * basis1[(b * NNODES + src) * HDIM + hh];
    atomicAdd(&h[dst * HDIM + hh], norm * acc);
}

__global__ __launch_bounds__(256) void relu_kernel(float* __restrict__ h,
                                                   const float* __restrict__ root1,
                                                   const float* __restrict__ bias1) {
    int i = blockIdx.x * blockDim.x + threadIdx.x;
    if (i >= NNODES * HDIM) return;
    float v = h[i] + root1[i] + bias1[i & (HDIM - 1)];
    h[i] = v > 0.f ? v : 0.f;
}

__global__ __launch_bounds__(256) void layer2_flat(const int* __restrict__ ei,
                                                   const int* __restrict__ et,
                                                   const float* __restrict__ h,
                                                   const float* __restrict__ w2t,
                                                   const int* __restrict__ deg,
                                                   float* __restrict__ out_tmp) {
    long long idx = (long long)blockIdx.x * blockDim.x + threadIdx.x;
    if (idx >= (long long)NEDGE * NCLS) return;
    int e = (int)(idx >> 3);
    int c = (int)(idx & (NCLS - 1));
    int src = ei[e];
    int dst = ei[NEDGE + e];
    int r   = et[e];
    float norm = 1.0f / (float)deg[dst * NREL + r];
    const float4* __restrict__ hp = (const float4*)h + src * 4;
    const float4* __restrict__ wp = (const float4*)w2t + (r * NCLS + c) * 4;
    float a = 0.f;
#pragma unroll
    for (int qq = 0; qq < 4; ++qq) {
        float4 hv = hp[qq];
        float4 wv = wp[qq];
        a = fmaf(hv.x, wv.x, a);
        a = fmaf(hv.y, wv.y, a);
        a = fmaf(hv.z, wv.z, a);
        a = fmaf(hv.w, wv.w, a);
    }
    atomicAdd(&out_tmp[dst * NCLS + c], norm * a);
}

__global__ __launch_bounds__(256) void final_kernel(const float* __restrict__ out_tmp,
                                                    const float* __restrict__ h,
                                                    const float* __restrict__ root2,
                                                    const float* __restrict__ bias2,
                                                    float* __restrict__ out) {
    int n = blockIdx.x * blockDim.x + threadIdx.x;
    if (n >= NNODES) return;
    float hv[HDIM];
#pragma unroll
    for (int i = 0; i < HDIM; ++i) hv[i] = h[n * HDIM + i];
    float v[NCLS];
    float mx = -1e30f;
#pragma unroll
    for (int c = 0; c < NCLS; ++c) {
        float acc = out_tmp[n * NCLS + c] + bias2[c];
#pragma unroll
        for (int i = 0; i < HDIM; ++i) acc += hv[i] * root2[i * NCLS + c];
        v[c] = acc;
        mx = fmaxf(mx, acc);
    }
    float s = 0.f;
#pragma unroll
    for (int c = 0; c < NCLS; ++c) s += expf(v[c] - mx);
    float ls = logf(s);
#pragma unroll
    for (int c = 0; c < NCLS; ++c) out[n * NCLS + c] = v[c] - mx - ls;
}

extern "C" void kernel_launch(void* const* d_in, const int* in_sizes, int n_in,
                              void* d_out, int out_size, void* d_ws, size_t ws_size,
                              hipStream_t stream) {
    const int*   ei     = (const int*)d_in[0];
    const int*   et     = (const int*)d_in[1];
    const float* basis1 = (const float*)d_in[2];
    const float* comp1  = (const float*)d_in[3];
    const float* root1  = (const float*)d_in[4];
    const float* bias1  = (const float*)d_in[5];
    const float* basis2 = (const float*)d_in[6];
    const float* comp2  = (const float*)d_in[7];
    const float* root2  = (const float*)d_in[8];
    const float* bias2  = (const float*)d_in[9];
    float* out = (float*)d_out;

    // ---------- primary layout (4-byte words) ----------
    int*   cnt_s  = (int*)d_ws;                         // N (zero)
    int*   cnt_d  = cnt_s + NNODES;                     // N (zero)
    int*   offs_s = cnt_d + NNODES;                     // N
    int*   offs_d = offs_s + NNODES;                    // N
    int*   cur_s  = offs_d + NNODES;                    // N
    int*   cur_d  = cur_s + NNODES;                     // N
    int*   bsum_s = cur_d + NNODES;                     // NB1
    int*   bpre_s = bsum_s + NB1;                       // NB1
    int*   bsum_d = bpre_s + NB1;                       // NB1
    int*   bpre_d = bsum_d + NB1;                       // NB1
    int2*  s_rec  = (int2*)(bpre_d + NB1);              // E int2  (offset 300784 words, even)
    int2*  d_rec  = s_rec + NEDGE;                      // E int2
    float* d_norm = (float*)(d_rec + NEDGE);            // E
    float* m1d    = d_norm + NEDGE;                     // E*H (offset % 4 == 0 -> 16B aligned)
    float* h      = m1d + (size_t)NEDGE * HDIM;         // N*H
    float* w2t    = h + (size_t)NNODES * HDIM;          // R*H*C
    float* r2t    = w2t + (size_t)NREL * HDIM * NCLS;   // H*C
    size_t total_words = 6 * (size_t)NNODES + 4 * NB1 + 5 * (size_t)NEDGE +
                         (size_t)NEDGE * HDIM + (size_t)NNODES * HDIM +
                         (size_t)NREL * HDIM * NCLS + HDIM * NCLS;

    if (ws_size >= total_words * sizeof(float)) {
        hipMemsetAsync(d_ws, 0, 2 * NNODES * sizeof(int), stream);
        cnt_kernel<<<(NEDGE + 255) / 256, 256, 0, stream>>>(ei, cnt_s, cnt_d);
        scan1_batch<<<2 * NB1, SCAN_B, 0, stream>>>(cnt_s, cnt_d, offs_s, offs_d, bsum_s, bsum_d);
        scan2_batch<<<2, SCAN_B, 0, stream>>>(bsum_s, bsum_d, bpre_s, bpre_d);
        scanadd_batch<<<2 * NB1, SCAN_B, 0, stream>>>(offs_s, offs_d, bpre_s, bpre_d, cur_s, cur_d);
        scatter2_kernel<<<(NEDGE + 255) / 256, 256, 0, stream>>>(ei, et, cur_s, cur_d, s_rec, d_rec);
        norm_kernel<<<(NEDGE + 255) / 256, 256, 0, stream>>>(d_rec, offs_d, cnt_d, d_norm);

        msg1_lds<<<NNODES / GS, 256, 0, stream>>>(basis1, comp1, offs_s, cnt_s, s_rec, m1d);
        gather1_flat<<<(NNODES * 4 + 255) / 256, 256, 0, stream>>>(m1d, d_norm, offs_d, cnt_d,
                                                                   root1, bias1, h);
        w2_kernel<<<(NREL * HDIM * NCLS + 255) / 256, 256, 0, stream>>>(basis2, comp2, root2,
                                                                        w2t, r2t);
        layer2f_flat<<<(NNODES * NCLS + 255) / 256, 256, 0, stream>>>(
            h, w2t, r2t, offs_d, cnt_d, d_rec, d_norm, bias2, out);
        return;
    }

    // ---------- fallback: flat atomic path (~23.3 MB) ----------
    {
        int*   deg_f   = (int*)d_ws;                               // N*R  (zero)
        float* h_f     = (float*)(deg_f + (size_t)NNODES * NREL);  // N*H  (zero)
        float* out_tmp = h_f + (size_t)NNODES * HDIM;              // N*C  (zero)
        size_t zw = (size_t)NNODES * NREL + NNODES * HDIM + NNODES * NCLS;
        float* w2t_f   = out_tmp + (size_t)NNODES * NCLS;          // R*H*C
        float* r2t_f   = w2t_f + (size_t)NREL * HDIM * NCLS;       // H*C

        hipMemsetAsync(d_ws, 0, zw * sizeof(float), stream);
        degcnt_fb<<<(NEDGE + 255) / 256, 256, 0, stream>>>(ei, et, deg_f);
        layer1_flat<<<((size_t)NEDGE * HDIM + 255) / 256, 256, 0, stream>>>(
            ei, et, basis1, comp1, deg_f, h_f);
        relu_kernel<<<(NNODES * HDIM + 255) / 256, 256, 0, stream>>>(h_f, root1, bias1);
        w2_kernel<<<(NREL * HDIM * NCLS + 255) / 256, 256, 0, stream>>>(basis2, comp2, root2,
                                                                        w2t_f, r2t_f);
        layer2_flat<<<((size_t)NEDGE * NCLS + 255) / 256, 256, 0, stream>>>(
            ei, et, h_f, w2t_f, deg_f, out_tmp);
        final_kernel<<<(NNODES + 255) / 256, 256, 0, stream>>>(out_tmp, h_f, root2, bias2, out);
    }
}

// Round 6
// 220.070 us; speedup vs baseline: 1.8199x; 1.5615x over previous
//
#include <hip/hip_runtime.h>

#define NNODES 50000
#define NREL   90
#define NEDGE  800000
#define HDIM   16
#define NBASIS 30
#define NCLS   8
#define NPART  392    // partitions = node>>7 ; 391 used (0..390), padded
#define CH     4096   // edges per pass-1 block
#define P1BLK  ((NEDGE + CH - 1) / CH)    // 196
#define CAP    3072   // max items per partition in pass 2 (mean 2048, sigma ~45)
#define GS     8      // srcs per msg1 block
#define BSTR   484    // padded per-src basis slice stride (480 + 4)

// ============================================================
// partition histograms (LDS-aggregated; src and dst in one pass)
// ============================================================
__global__ __launch_bounds__(256) void histp_kernel(const int* __restrict__ ei,
                                                    int* __restrict__ hist_s,
                                                    int* __restrict__ hist_d) {
    __shared__ int hs[NPART], hd[NPART];
    for (int i = threadIdx.x; i < NPART; i += 256) { hs[i] = 0; hd[i] = 0; }
    __syncthreads();
    int base = blockIdx.x * CH;
    for (int i = 0; i < CH; i += 256) {
        int e = base + i + threadIdx.x;
        if (e < NEDGE) {
            atomicAdd(&hs[ei[e] >> 7], 1);
            atomicAdd(&hd[ei[NEDGE + e] >> 7], 1);
        }
    }
    __syncthreads();
    for (int i = threadIdx.x; i < NPART; i += 256) {
        if (hs[i]) atomicAdd(&hist_s[i], hs[i]);
        if (hd[i]) atomicAdd(&hist_d[i], hd[i]);
    }
}

// grid = 2: exclusive scan of the 392 partition counts -> pstart, gcur
__global__ __launch_bounds__(256) void scanp_kernel(const int* __restrict__ hist_s,
                                                    const int* __restrict__ hist_d,
                                                    int* __restrict__ pstart_s,
                                                    int* __restrict__ pstart_d,
                                                    int* __restrict__ gcur_s,
                                                    int* __restrict__ gcur_d) {
    __shared__ int tmp[NPART];
    const int* hist = blockIdx.x ? hist_d : hist_s;
    int* pstart = blockIdx.x ? pstart_d : pstart_s;
    int* gcur   = blockIdx.x ? gcur_d   : gcur_s;
    for (int i = threadIdx.x; i < NPART; i += 256) tmp[i] = hist[i];
    __syncthreads();
    if (threadIdx.x == 0) {
        int run = 0;
        for (int p = 0; p < NPART; ++p) { int v = tmp[p]; tmp[p] = run; run += v; }
    }
    __syncthreads();
    for (int i = threadIdx.x; i < NPART; i += 256) { pstart[i] = tmp[i]; gcur[i] = tmp[i]; }
}

// ============================================================
// src-sort pass 1: partition edges by src>>7; block-local LDS ordering ->
// coalesced partition-grouped writes. record = (dst|(r<<16), src)
// ============================================================
__global__ __launch_bounds__(256) void p1s_kernel(const int* __restrict__ ei,
                                                  const int* __restrict__ et,
                                                  int* __restrict__ gcur_s,
                                                  int2* __restrict__ sp1) {
    __shared__ int2 sorted[CH];
    __shared__ int hist[NPART], loff[NPART], cur[NPART], gbase[NPART];
    int base = blockIdx.x * CH;
    int nitems = min(CH, NEDGE - base);
    for (int i = threadIdx.x; i < NPART; i += 256) hist[i] = 0;
    __syncthreads();
    for (int i = 0; i < CH; i += 256) {
        int ii = i + threadIdx.x;
        if (ii < nitems) atomicAdd(&hist[ei[base + ii] >> 7], 1);
    }
    __syncthreads();
    if (threadIdx.x == 0) {
        int run = 0;
        for (int p = 0; p < NPART; ++p) { loff[p] = run; run += hist[p]; }
    }
    __syncthreads();
    for (int p = threadIdx.x; p < NPART; p += 256) {
        cur[p] = loff[p];
        if (hist[p]) gbase[p] = atomicAdd(&gcur_s[p], hist[p]);
    }
    __syncthreads();
    for (int i = 0; i < CH; i += 256) {
        int ii = i + threadIdx.x;
        if (ii < nitems) {
            int e = base + ii;
            int src = ei[e], dst = ei[NEDGE + e], r = et[e];
            int rk = atomicAdd(&cur[src >> 7], 1);
            sorted[rk] = make_int2(dst | (r << 16), src);
        }
    }
    __syncthreads();
    for (int s = threadIdx.x; s < nitems; s += 256) {
        int2 it = sorted[s];
        int p = it.y >> 7;
        sp1[gbase[p] + (s - loff[p])] = it;
    }
}

// ============================================================
// src-sort pass 2: exact count-sort by src low-7 in LDS.
// emits sA[j]=dst|(r<<16), sB[j]=src|(r<<16), offs_s/cnt_s per src.
// ============================================================
__global__ __launch_bounds__(256) void p2s_kernel(const int* __restrict__ pstart_s,
                                                  const int2* __restrict__ sp1,
                                                  int* __restrict__ sA,
                                                  int* __restrict__ sB,
                                                  int* __restrict__ offs_s,
                                                  int* __restrict__ cnt_s) {
    __shared__ int2 sorted[CAP];
    __shared__ int h[128], off[128], cur[128];
    int p = blockIdx.x;
    int base = pstart_s[p];
    int n = min(pstart_s[p + 1] - base, CAP);
    for (int k = threadIdx.x; k < 128; k += 256) h[k] = 0;
    __syncthreads();
    for (int s = threadIdx.x; s < n; s += 256)
        atomicAdd(&h[sp1[base + s].y & 127], 1);
    __syncthreads();
    if (threadIdx.x == 0) {
        int run = 0;
        for (int k = 0; k < 128; ++k) { off[k] = run; run += h[k]; }
    }
    __syncthreads();
    for (int k = threadIdx.x; k < 128; k += 256) cur[k] = off[k];
    __syncthreads();
    for (int s = threadIdx.x; s < n; s += 256) {
        int2 it = sp1[base + s];
        int rk = atomicAdd(&cur[it.y & 127], 1);
        sorted[rk] = it;
    }
    __syncthreads();
    for (int s = threadIdx.x; s < n; s += 256) {
        int2 it = sorted[s];
        int r = it.x >> 16;
        sA[base + s] = it.x;
        sB[base + s] = it.y | (r << 16);
    }
    for (int k = threadIdx.x; k < 128; k += 256) {
        int node = (p << 7) + k;
        if (node < NNODES) { offs_s[node] = base + off[k]; cnt_s[node] = h[k]; }
    }
}

// ============================================================
// dst-sort pass 1: partition j-records by dst>>7.
// record = (sB[j] | part<<23, j | dlow7<<20)
// ============================================================
__global__ __launch_bounds__(256) void p1d_kernel(const int* __restrict__ sA,
                                                  const int* __restrict__ sB,
                                                  int* __restrict__ gcur_d,
                                                  int2* __restrict__ dp1) {
    __shared__ int2 sorted[CH];
    __shared__ int hist[NPART], loff[NPART], cur[NPART], gbase[NPART];
    int base = blockIdx.x * CH;
    int nitems = min(CH, NEDGE - base);
    for (int i = threadIdx.x; i < NPART; i += 256) hist[i] = 0;
    __syncthreads();
    for (int i = 0; i < CH; i += 256) {
        int ii = i + threadIdx.x;
        if (ii < nitems) atomicAdd(&hist[(sA[base + ii] & 0xFFFF) >> 7], 1);
    }
    __syncthreads();
    if (threadIdx.x == 0) {
        int run = 0;
        for (int p = 0; p < NPART; ++p) { loff[p] = run; run += hist[p]; }
    }
    __syncthreads();
    for (int p = threadIdx.x; p < NPART; p += 256) {
        cur[p] = loff[p];
        if (hist[p]) gbase[p] = atomicAdd(&gcur_d[p], hist[p]);
    }
    __syncthreads();
    for (int i = 0; i < CH; i += 256) {
        int ii = i + threadIdx.x;
        if (ii < nitems) {
            int j = base + ii;
            int dst = sA[j] & 0xFFFF;
            int pp = dst >> 7;
            int rk = atomicAdd(&cur[pp], 1);
            sorted[rk] = make_int2(sB[j] | (pp << 23), j | ((dst & 127) << 20));
        }
    }
    __syncthreads();
    for (int s = threadIdx.x; s < nitems; s += 256) {
        int2 it = sorted[s];
        unsigned p = ((unsigned)it.x) >> 23;
        dp1[gbase[p] + (s - loff[p])] = it;
    }
}

// ============================================================
// dst-sort pass 2: exact count-sort by dst low-7 in LDS; computes per-edge
// norm = 1/#{same (dst,r)} from in-LDS segments.
// emits d_rec[k]=(src|(r<<16), j), d_norm, offs_d/cnt_d.
// ============================================================
__global__ __launch_bounds__(256) void p2d_kernel(const int* __restrict__ pstart_d,
                                                  const int2* __restrict__ dp1,
                                                  int2* __restrict__ d_rec,
                                                  float* __restrict__ d_norm,
                                                  int* __restrict__ offs_d,
                                                  int* __restrict__ cnt_d) {
    __shared__ int2 sorted[CAP];
    __shared__ int h[128], off[128], cur[128];
    int p = blockIdx.x;
    int base = pstart_d[p];
    int n = min(pstart_d[p + 1] - base, CAP);
    for (int k = threadIdx.x; k < 128; k += 256) h[k] = 0;
    __syncthreads();
    for (int s = threadIdx.x; s < n; s += 256)
        atomicAdd(&h[(dp1[base + s].y >> 20) & 127], 1);
    __syncthreads();
    if (threadIdx.x == 0) {
        int run = 0;
        for (int k = 0; k < 128; ++k) { off[k] = run; run += h[k]; }
    }
    __syncthreads();
    for (int k = threadIdx.x; k < 128; k += 256) cur[k] = off[k];
    __syncthreads();
    for (int s = threadIdx.x; s < n; s += 256) {
        int2 it = dp1[base + s];
        int rk = atomicAdd(&cur[(it.y >> 20) & 127], 1);
        sorted[rk] = it;
    }
    __syncthreads();
    for (int s = threadIdx.x; s < n; s += 256) {
        int2 it = sorted[s];
        int k = (it.y >> 20) & 127;
        int r = (it.x >> 16) & 127;
        int o = off[k], oe = o + h[k];
        int c = 0;
        for (int kk = o; kk < oe; ++kk)
            c += (((sorted[kk].x >> 16) & 127) == r);
        d_rec[base + s] = make_int2(it.x & 0x7FFFFF, it.y & 0xFFFFF);
        d_norm[base + s] = 1.0f / (float)c;
    }
    for (int k = threadIdx.x; k < 128; k += 256) {
        int node = (p << 7) + k;
        if (node < NNODES) { offs_d[node] = base + off[k]; cnt_d[node] = h[k]; }
    }
}

// ============================================================
// layer-1 messages: basis1 slices of GS=8 srcs staged in LDS (streaming fill),
// comp1 in LDS; unnormalized message written SEQUENTIALLY at j.
// ============================================================
__global__ __launch_bounds__(256) void msg1_lds(const float* __restrict__ basis1,
                                                const float* __restrict__ comp1,
                                                const int* __restrict__ offs_s,
                                                const int* __restrict__ cnt_s,
                                                const int* __restrict__ sB,
                                                float* __restrict__ m1) {
    __shared__ float bs[GS * BSTR];
    __shared__ float cs[NREL * NBASIS];
    int src0 = blockIdx.x * GS;
    int t = threadIdx.x;
    for (int i = t; i < (NREL * NBASIS) / 4; i += 256)
        ((float4*)cs)[i] = ((const float4*)comp1)[i];
    for (int i4 = t; i4 < NBASIS * (GS * 4); i4 += 256) {
        int b = i4 >> 5;
        int w = i4 & 31;
        float4 v = ((const float4*)basis1)[(size_t)b * (NNODES * 4) + (size_t)src0 * 4 + w];
        int s = w >> 2;
        int q = w & 3;
        *((float4*)(bs + s * BSTR + b * HDIM) + q) = v;
    }
    __syncthreads();
    int n0 = offs_s[src0];
    int lastS = src0 + GS - 1;
    int n1 = offs_s[lastS] + cnt_s[lastS];
    for (int ii = n0 * 4 + t; ii < n1 * 4; ii += 256) {
        int j = ii >> 2;
        int q = ii & 3;
        int pk = sB[j];
        int src = pk & 0xFFFF;
        int r   = pk >> 16;
        const float* __restrict__ bw = bs + (src - src0) * BSTR + q * 4;
        const float* __restrict__ cp = cs + r * NBASIS;
        float4 acc = make_float4(0.f, 0.f, 0.f, 0.f);
#pragma unroll
        for (int b = 0; b < NBASIS; ++b) {
            float4 bv = *(const float4*)(bw + b * HDIM);
            float  cb = cp[b];
            acc.x = fmaf(cb, bv.x, acc.x);
            acc.y = fmaf(cb, bv.y, acc.y);
            acc.z = fmaf(cb, bv.z, acc.z);
            acc.w = fmaf(cb, bv.w, acc.w);
        }
        ((float4*)m1)[(size_t)j * 4 + q] = acc;
    }
}

// ============================================================
// layer-1 gather: thread per (dst, h-quad); gathers m1 via j = d_rec[k].y
// (4 q-lanes share one 64B line); fuses norm + root1 + bias1 + relu.
// ============================================================
__global__ __launch_bounds__(256) void gather1_flat(const float* __restrict__ m1,
                                                    const int2* __restrict__ d_rec,
                                                    const float* __restrict__ d_norm,
                                                    const int* __restrict__ offs_d,
                                                    const int* __restrict__ cnt_d,
                                                    const float* __restrict__ root1,
                                                    const float* __restrict__ bias1,
                                                    float* __restrict__ h) {
    int idx = blockIdx.x * blockDim.x + threadIdx.x;
    if (idx >= NNODES * 4) return;
    int dst = idx >> 2;
    int q   = idx & 3;
    int k0 = offs_d[dst];
    int k1 = k0 + cnt_d[dst];
    float4 acc = make_float4(0.f, 0.f, 0.f, 0.f);
    for (int k = k0; k < k1; ++k) {
        int j = d_rec[k].y;
        float nm = d_norm[k];
        float4 v = ((const float4*)m1)[(size_t)j * 4 + q];
        acc.x = fmaf(nm, v.x, acc.x);
        acc.y = fmaf(nm, v.y, acc.y);
        acc.z = fmaf(nm, v.z, acc.z);
        acc.w = fmaf(nm, v.w, acc.w);
    }
    float4 rt = ((const float4*)root1)[idx];
    float4 bi = ((const float4*)bias1)[q];
    float4 o;
    o.x = fmaxf(acc.x + rt.x + bi.x, 0.f);
    o.y = fmaxf(acc.y + rt.y + bi.y, 0.f);
    o.z = fmaxf(acc.z + rt.z + bi.z, 0.f);
    o.w = fmaxf(acc.w + rt.w + bi.w, 0.f);
    ((float4*)h)[idx] = o;
}

// ---------------- W2 transposed: w2t[r][c][hh] ; r2t[c][hh] ----------------
__global__ __launch_bounds__(256) void w2_kernel(const float* __restrict__ basis2,
                                                 const float* __restrict__ comp2,
                                                 const float* __restrict__ root2,
                                                 float* __restrict__ w2t,
                                                 float* __restrict__ r2t) {
    int i = blockIdx.x * blockDim.x + threadIdx.x;
    if (i >= NREL * HDIM * NCLS) return;
    int kk = i & (HDIM - 1);
    int c  = (i >> 4) & (NCLS - 1);
    int r  = i >> 7;
    float acc = 0.f;
#pragma unroll
    for (int b = 0; b < NBASIS; ++b)
        acc += comp2[r * NBASIS + b] * basis2[(b * HDIM + kk) * NCLS + c];
    w2t[i] = acc;
    if (i < HDIM * NCLS) {
        int c2 = i >> 4;
        int k2 = i & (HDIM - 1);
        r2t[i] = root2[k2 * NCLS + c2];
    }
}

// ============================================================
// layer 2 fused: thread per (dst, c); fused root2 + bias2 + log_softmax.
// ============================================================
__global__ __launch_bounds__(256) void layer2f_flat(const float* __restrict__ h,
                                                    const float* __restrict__ w2t,
                                                    const float* __restrict__ r2t,
                                                    const int* __restrict__ offs_d,
                                                    const int* __restrict__ cnt_d,
                                                    const int2* __restrict__ d_rec,
                                                    const float* __restrict__ d_norm,
                                                    const float* __restrict__ bias2,
                                                    float* __restrict__ out) {
    int idx = blockIdx.x * blockDim.x + threadIdx.x;
    if (idx >= NNODES * NCLS) return;
    int dst = idx >> 3;
    int c   = idx & (NCLS - 1);
    int k0 = offs_d[dst];
    int k1 = k0 + cnt_d[dst];
    const float4* __restrict__ h4 = (const float4*)h;
    const float4* __restrict__ w4 = (const float4*)w2t;
    float acc = 0.f;
    for (int k = k0; k < k1; ++k) {
        int2  rec = d_rec[k];
        float nm  = d_norm[k];
        int src = rec.x & 0xFFFF;
        int r   = rec.x >> 16;
        const float4* __restrict__ hp = h4 + src * 4;
        const float4* __restrict__ wp = w4 + (r * NCLS + c) * 4;
        float a = 0.f;
#pragma unroll
        for (int qq = 0; qq < 4; ++qq) {
            float4 hv = hp[qq];
            float4 wv = wp[qq];
            a = fmaf(hv.x, wv.x, a);
            a = fmaf(hv.y, wv.y, a);
            a = fmaf(hv.z, wv.z, a);
            a = fmaf(hv.w, wv.w, a);
        }
        acc = fmaf(nm, a, acc);
    }
    float v = acc + bias2[c];
    const float4* __restrict__ hd = h4 + dst * 4;
    const float4* __restrict__ rp = (const float4*)r2t + c * 4;
#pragma unroll
    for (int qq = 0; qq < 4; ++qq) {
        float4 hv = hd[qq];
        float4 rv = rp[qq];
        v = fmaf(hv.x, rv.x, v);
        v = fmaf(hv.y, rv.y, v);
        v = fmaf(hv.z, rv.z, v);
        v = fmaf(hv.w, rv.w, v);
    }
    float mx = v;
    mx = fmaxf(mx, __shfl_xor(mx, 1));
    mx = fmaxf(mx, __shfl_xor(mx, 2));
    mx = fmaxf(mx, __shfl_xor(mx, 4));
    float s = expf(v - mx);
    s += __shfl_xor(s, 1);
    s += __shfl_xor(s, 2);
    s += __shfl_xor(s, 4);
    out[idx] = v - mx - logf(s);
}

// ============================================================
// fallback (flat atomic path; needs ~23.3 MB)
// ============================================================
__global__ __launch_bounds__(256) void degcnt_fb(const int* __restrict__ ei,
                                                 const int* __restrict__ et,
                                                 int* __restrict__ deg) {
    int e = blockIdx.x * blockDim.x + threadIdx.x;
    if (e >= NEDGE) return;
    atomicAdd(&deg[ei[NEDGE + e] * NREL + et[e]], 1);
}

__global__ __launch_bounds__(256) void layer1_flat(const int* __restrict__ ei,
                                                   const int* __restrict__ et,
                                                   const float* __restrict__ basis1,
                                                   const float* __restrict__ comp1,
                                                   const int* __restrict__ deg,
                                                   float* __restrict__ h) {
    long long idx = (long long)blockIdx.x * blockDim.x + threadIdx.x;
    if (idx >= (long long)NEDGE * HDIM) return;
    int e  = (int)(idx >> 4);
    int hh = (int)(idx & (HDIM - 1));
    int src = ei[e];
    int dst = ei[NEDGE + e];
    int r   = et[e];
    float norm = 1.0f / (float)deg[dst * NREL + r];
    const float* __restrict__ cp = comp1 + r * NBASIS;
    float acc = 0.f;
#pragma unroll
    for (int b = 0; b < NBASIS; ++b)
        acc += cp[b] * basis1[(b * NNODES + src) * HDIM + hh];
    atomicAdd(&h[dst * HDIM + hh], norm * acc);
}

__global__ __launch_bounds__(256) void relu_kernel(float* __restrict__ h,
                                                   const float* __restrict__ root1,
                                                   const float* __restrict__ bias1) {
    int i = blockIdx.x * blockDim.x + threadIdx.x;
    if (i >= NNODES * HDIM) return;
    float v = h[i] + root1[i] + bias1[i & (HDIM - 1)];
    h[i] = v > 0.f ? v : 0.f;
}

__global__ __launch_bounds__(256) void layer2_flat(const int* __restrict__ ei,
                                                   const int* __restrict__ et,
                                                   const float* __restrict__ h,
                                                   const float* __restrict__ w2t,
                                                   const int* __restrict__ deg,
                                                   float* __restrict__ out_tmp) {
    long long idx = (long long)blockIdx.x * blockDim.x + threadIdx.x;
    if (idx >= (long long)NEDGE * NCLS) return;
    int e = (int)(idx >> 3);
    int c = (int)(idx & (NCLS - 1));
    int src = ei[e];
    int dst = ei[NEDGE + e];
    int r   = et[e];
    float norm = 1.0f / (float)deg[dst * NREL + r];
    const float4* __restrict__ hp = (const float4*)h + src * 4;
    const float4* __restrict__ wp = (const float4*)w2t + (r * NCLS + c) * 4;
    float a = 0.f;
#pragma unroll
    for (int qq = 0; qq < 4; ++qq) {
        float4 hv = hp[qq];
        float4 wv = wp[qq];
        a = fmaf(hv.x, wv.x, a);
        a = fmaf(hv.y, wv.y, a);
        a = fmaf(hv.z, wv.z, a);
        a = fmaf(hv.w, wv.w, a);
    }
    atomicAdd(&out_tmp[dst * NCLS + c], norm * a);
}

__global__ __launch_bounds__(256) void final_kernel(const float* __restrict__ out_tmp,
                                                    const float* __restrict__ h,
                                                    const float* __restrict__ root2,
                                                    const float* __restrict__ bias2,
                                                    float* __restrict__ out) {
    int n = blockIdx.x * blockDim.x + threadIdx.x;
    if (n >= NNODES) return;
    float hv[HDIM];
#pragma unroll
    for (int i = 0; i < HDIM; ++i) hv[i] = h[n * HDIM + i];
    float v[NCLS];
    float mx = -1e30f;
#pragma unroll
    for (int c = 0; c < NCLS; ++c) {
        float acc = out_tmp[n * NCLS + c] + bias2[c];
#pragma unroll
        for (int i = 0; i < HDIM; ++i) acc += hv[i] * root2[i * NCLS + c];
        v[c] = acc;
        mx = fmaxf(mx, acc);
    }
    float s = 0.f;
#pragma unroll
    for (int c = 0; c < NCLS; ++c) s += expf(v[c] - mx);
    float ls = logf(s);
#pragma unroll
    for (int c = 0; c < NCLS; ++c) out[n * NCLS + c] = v[c] - mx - ls;
}

extern "C" void kernel_launch(void* const* d_in, const int* in_sizes, int n_in,
                              void* d_out, int out_size, void* d_ws, size_t ws_size,
                              hipStream_t stream) {
    const int*   ei     = (const int*)d_in[0];
    const int*   et     = (const int*)d_in[1];
    const float* basis1 = (const float*)d_in[2];
    const float* comp1  = (const float*)d_in[3];
    const float* root1  = (const float*)d_in[4];
    const float* bias1  = (const float*)d_in[5];
    const float* basis2 = (const float*)d_in[6];
    const float* comp2  = (const float*)d_in[7];
    const float* root2  = (const float*)d_in[8];
    const float* bias2  = (const float*)d_in[9];
    float* out = (float*)d_out;

    // ---------- primary layout (4-byte words; int2 arrays at even offsets) ----------
    int*   hist_s   = (int*)d_ws;                       // NPART (zero)
    int*   hist_d   = hist_s + NPART;                   // NPART (zero)
    int*   pstart_s = hist_d + NPART;                   // NPART
    int*   pstart_d = pstart_s + NPART;                 // NPART
    int*   gcur_s   = pstart_d + NPART;                 // NPART
    int*   gcur_d   = gcur_s + NPART;                   // NPART  -> 2352 words (even)
    int2*  sp1      = (int2*)(gcur_d + NPART);          // E int2
    int2*  dp1      = sp1 + NEDGE;                      // E int2
    int*   sA       = (int*)(dp1 + NEDGE);              // E
    int*   sB       = sA + NEDGE;                       // E
    int*   offs_s   = sB + NEDGE;                       // N
    int*   cnt_s    = offs_s + NNODES;                  // N
    int*   offs_d   = cnt_s + NNODES;                   // N
    int*   cnt_d    = offs_d + NNODES;                  // N    -> even offset
    int2*  d_rec    = (int2*)(cnt_d + NNODES);          // E int2
    float* d_norm   = (float*)(d_rec + NEDGE);          // E
    float* m1       = d_norm + NEDGE;                   // E*H (offset %4==0 -> 16B aligned)
    float* h        = m1 + (size_t)NEDGE * HDIM;        // N*H
    float* w2t      = h + (size_t)NNODES * HDIM;        // R*H*C
    float* r2t      = w2t + (size_t)NREL * HDIM * NCLS; // H*C
    size_t total_words = 6 * (size_t)NPART + 8 * (size_t)NEDGE + 4 * (size_t)NNODES +
                         (size_t)NEDGE * HDIM + (size_t)NNODES * HDIM +
                         (size_t)NREL * HDIM * NCLS + HDIM * NCLS;

    if (ws_size >= total_words * sizeof(float)) {
        hipMemsetAsync(hist_s, 0, 2 * NPART * sizeof(int), stream);
        histp_kernel<<<P1BLK, 256, 0, stream>>>(ei, hist_s, hist_d);
        scanp_kernel<<<2, 256, 0, stream>>>(hist_s, hist_d, pstart_s, pstart_d, gcur_s, gcur_d);
        p1s_kernel<<<P1BLK, 256, 0, stream>>>(ei, et, gcur_s, sp1);
        p2s_kernel<<<NPART - 1, 256, 0, stream>>>(pstart_s, sp1, sA, sB, offs_s, cnt_s);
        p1d_kernel<<<P1BLK, 256, 0, stream>>>(sA, sB, gcur_d, dp1);
        p2d_kernel<<<NPART - 1, 256, 0, stream>>>(pstart_d, dp1, d_rec, d_norm, offs_d, cnt_d);

        msg1_lds<<<NNODES / GS, 256, 0, stream>>>(basis1, comp1, offs_s, cnt_s, sB, m1);
        gather1_flat<<<(NNODES * 4 + 255) / 256, 256, 0, stream>>>(
            m1, d_rec, d_norm, offs_d, cnt_d, root1, bias1, h);
        w2_kernel<<<(NREL * HDIM * NCLS + 255) / 256, 256, 0, stream>>>(basis2, comp2, root2,
                                                                        w2t, r2t);
        layer2f_flat<<<(NNODES * NCLS + 255) / 256, 256, 0, stream>>>(
            h, w2t, r2t, offs_d, cnt_d, d_rec, d_norm, bias2, out);
        return;
    }

    // ---------- fallback: flat atomic path (~23.3 MB) ----------
    {
        int*   deg_f   = (int*)d_ws;                               // N*R  (zero)
        float* h_f     = (float*)(deg_f + (size_t)NNODES * NREL);  // N*H  (zero)
        float* out_tmp = h_f + (size_t)NNODES * HDIM;              // N*C  (zero)
        size_t zw = (size_t)NNODES * NREL + NNODES * HDIM + NNODES * NCLS;
        float* w2t_f   = out_tmp + (size_t)NNODES * NCLS;          // R*H*C
        float* r2t_f   = w2t_f + (size_t)NREL * HDIM * NCLS;       // H*C

        hipMemsetAsync(d_ws, 0, zw * sizeof(float), stream);
        degcnt_fb<<<(NEDGE + 255) / 256, 256, 0, stream>>>(ei, et, deg_f);
        layer1_flat<<<((size_t)NEDGE * HDIM + 255) / 256, 256, 0, stream>>>(
            ei, et, basis1, comp1, deg_f, h_f);
        relu_kernel<<<(NNODES * HDIM + 255) / 256, 256, 0, stream>>>(h_f, root1, bias1);
        w2_kernel<<<(NREL * HDIM * NCLS + 255) / 256, 256, 0, stream>>>(basis2, comp2, root2,
                                                                        w2t_f, r2t_f);
        layer2_flat<<<((size_t)NEDGE * NCLS + 255) / 256, 256, 0, stream>>>(
            ei, et, h_f, w2t_f, deg_f, out_tmp);
        final_kernel<<<(NNODES + 255) / 256, 256, 0, stream>>>(out_tmp, h_f, root2, bias2, out);
    }
}

// Round 7
// 193.814 us; speedup vs baseline: 2.0664x; 1.1355x over previous
//
#include <hip/hip_runtime.h>

#define NNODES 50000
#define NREL   90
#define NEDGE  800000
#define HDIM   16
#define NBASIS 30
#define NCLS   8
#define NPART  392    // partitions = node>>7 ; 0..390 used
#define CH     4096   // edges per pass-1 block
#define P1BLK  ((NEDGE + CH - 1) / CH)    // 196
#define CAP    3072   // max items per partition (mean 2048, sigma ~45)
#define GS     8      // srcs per msg1 block
#define BSTR   484    // padded per-src basis slice stride (480 + 4)

// ---------------- parallel inclusive scans in LDS ----------------
__device__ __forceinline__ void scan512_incl(int* sc) {
    int t = threadIdx.x;
#pragma unroll
    for (int d = 1; d < 512; d <<= 1) {
        int v0 = sc[t];
        int a0 = (t >= d) ? sc[t - d] : 0;
        int v1 = sc[t + 256];
        int a1 = sc[t + 256 - d];      // t+256 >= d always (d <= 256)
        __syncthreads();
        sc[t] = v0 + a0;
        sc[t + 256] = v1 + a1;
        __syncthreads();
    }
}

__device__ __forceinline__ void scan128_incl(int* sc) {
    int t = threadIdx.x;
#pragma unroll
    for (int d = 1; d < 128; d <<= 1) {
        int v = 0, a = 0;
        if (t < 128) { v = sc[t]; a = (t >= d) ? sc[t - d] : 0; }
        __syncthreads();
        if (t < 128) sc[t] = v + a;
        __syncthreads();
    }
}

// ============================================================
// partition histograms (src and dst in one pass)
// ============================================================
__global__ __launch_bounds__(256) void histp_kernel(const int* __restrict__ ei,
                                                    int* __restrict__ hist_s,
                                                    int* __restrict__ hist_d) {
    __shared__ int hs[NPART], hd[NPART];
    for (int i = threadIdx.x; i < NPART; i += 256) { hs[i] = 0; hd[i] = 0; }
    __syncthreads();
    int base = blockIdx.x * CH;
    for (int i = 0; i < CH; i += 256) {
        int e = base + i + threadIdx.x;
        if (e < NEDGE) {
            atomicAdd(&hs[ei[e] >> 7], 1);
            atomicAdd(&hd[ei[NEDGE + e] >> 7], 1);
        }
    }
    __syncthreads();
    for (int i = threadIdx.x; i < NPART; i += 256) {
        if (hs[i]) atomicAdd(&hist_s[i], hs[i]);
        if (hd[i]) atomicAdd(&hist_d[i], hd[i]);
    }
}

// grid = 2: exclusive scan of 392 partition counts -> pstart, gcur
__global__ __launch_bounds__(256) void scanp_kernel(const int* __restrict__ hist_s,
                                                    const int* __restrict__ hist_d,
                                                    int* __restrict__ pstart_s,
                                                    int* __restrict__ pstart_d,
                                                    int* __restrict__ gcur_s,
                                                    int* __restrict__ gcur_d) {
    __shared__ int sc[512];
    const int* hist = blockIdx.x ? hist_d : hist_s;
    int* pstart = blockIdx.x ? pstart_d : pstart_s;
    int* gcur   = blockIdx.x ? gcur_d   : gcur_s;
    int t = threadIdx.x;
    sc[t]       = (t < NPART) ? hist[t] : 0;
    sc[t + 256] = (t + 256 < NPART) ? hist[t + 256] : 0;
    __syncthreads();
    scan512_incl(sc);
    for (int i = t; i < NPART; i += 256) {
        int v = i ? sc[i - 1] : 0;
        pstart[i] = v;
        gcur[i] = v;
    }
}

// ============================================================
// dst-sort pass 1: partition raw edges by dst>>7.
// record: x = src | r<<16 , y = dst
// ============================================================
__global__ __launch_bounds__(256) void p1d_kernel(const int* __restrict__ ei,
                                                  const int* __restrict__ et,
                                                  int* __restrict__ gcur_d,
                                                  int2* __restrict__ dp1) {
    __shared__ int2 sorted[CH];
    __shared__ int hist[NPART], loff[NPART], cur[NPART], gbase[NPART];
    __shared__ int sc[512];
    int base = blockIdx.x * CH;
    int nitems = min(CH, NEDGE - base);
    int t = threadIdx.x;
    for (int i = t; i < NPART; i += 256) hist[i] = 0;
    __syncthreads();
    for (int i = 0; i < CH; i += 256) {
        int ii = i + t;
        if (ii < nitems) atomicAdd(&hist[ei[NEDGE + base + ii] >> 7], 1);
    }
    __syncthreads();
    sc[t]       = (t < NPART) ? hist[t] : 0;
    sc[t + 256] = (t + 256 < NPART) ? hist[t + 256] : 0;
    __syncthreads();
    scan512_incl(sc);
    for (int p = t; p < NPART; p += 256) {
        int lo = p ? sc[p - 1] : 0;
        loff[p] = lo;
        cur[p] = lo;
        if (hist[p]) gbase[p] = atomicAdd(&gcur_d[p], hist[p]);
    }
    __syncthreads();
    for (int i = 0; i < CH; i += 256) {
        int ii = i + t;
        if (ii < nitems) {
            int e = base + ii;
            int src = ei[e], dst = ei[NEDGE + e], r = et[e];
            int rk = atomicAdd(&cur[dst >> 7], 1);
            sorted[rk] = make_int2(src | (r << 16), dst);
        }
    }
    __syncthreads();
    for (int s = t; s < nitems; s += 256) {
        int2 it = sorted[s];
        int p = it.y >> 7;
        dp1[gbase[p] + (s - loff[p])] = it;
    }
}

// ============================================================
// dst-sort pass 2: count-sort by dst&127 in LDS; per-edge norm from
// in-LDS (dst,r) segments. emits d_rec[k]=(src|r<<16, dst), d_norm,
// offs_d/cnt_d.
// ============================================================
__global__ __launch_bounds__(256) void p2d_kernel(const int* __restrict__ pstart_d,
                                                  const int2* __restrict__ dp1,
                                                  int2* __restrict__ d_rec,
                                                  float* __restrict__ d_norm,
                                                  int* __restrict__ offs_d,
                                                  int* __restrict__ cnt_d) {
    __shared__ int2 sorted[CAP];
    __shared__ int h[128], off[128], cur[128], sc[128];
    int p = blockIdx.x;
    int base = pstart_d[p];
    int n = min(pstart_d[p + 1] - base, CAP);
    int t = threadIdx.x;
    if (t < 128) h[t] = 0;
    __syncthreads();
    for (int s = t; s < n; s += 256)
        atomicAdd(&h[dp1[base + s].y & 127], 1);
    __syncthreads();
    if (t < 128) sc[t] = h[t];
    __syncthreads();
    scan128_incl(sc);
    if (t < 128) {
        int lo = t ? sc[t - 1] : 0;
        off[t] = lo;
        cur[t] = lo;
    }
    __syncthreads();
    for (int s = t; s < n; s += 256) {
        int2 it = dp1[base + s];
        int rk = atomicAdd(&cur[it.y & 127], 1);
        sorted[rk] = it;
    }
    __syncthreads();
    for (int s = t; s < n; s += 256) {
        int2 it = sorted[s];
        int key = it.y & 127;
        int r = it.x >> 16;
        int o = off[key], oe = o + h[key];
        int c = 0;
        for (int kk = o; kk < oe; ++kk)
            c += ((sorted[kk].x >> 16) == r);
        d_rec[base + s] = it;
        d_norm[base + s] = 1.0f / (float)c;
    }
    if (t < 128) {
        int node = (p << 7) + t;
        if (node < NNODES) { offs_d[node] = base + off[t]; cnt_d[node] = h[t]; }
    }
}

// ============================================================
// src-sort pass 1: partition d_rec (k-order) by src>>7.
// record: x = src|r<<16 , y = k
// ============================================================
__global__ __launch_bounds__(256) void p1s_kernel(const int2* __restrict__ d_rec,
                                                  int* __restrict__ gcur_s,
                                                  int2* __restrict__ sp1) {
    __shared__ int2 sorted[CH];
    __shared__ int hist[NPART], loff[NPART], cur[NPART], gbase[NPART];
    __shared__ int sc[512];
    int base = blockIdx.x * CH;
    int nitems = min(CH, NEDGE - base);
    int t = threadIdx.x;
    for (int i = t; i < NPART; i += 256) hist[i] = 0;
    __syncthreads();
    for (int i = 0; i < CH; i += 256) {
        int ii = i + t;
        if (ii < nitems) atomicAdd(&hist[(d_rec[base + ii].x & 0xFFFF) >> 7], 1);
    }
    __syncthreads();
    sc[t]       = (t < NPART) ? hist[t] : 0;
    sc[t + 256] = (t + 256 < NPART) ? hist[t + 256] : 0;
    __syncthreads();
    scan512_incl(sc);
    for (int p = t; p < NPART; p += 256) {
        int lo = p ? sc[p - 1] : 0;
        loff[p] = lo;
        cur[p] = lo;
        if (hist[p]) gbase[p] = atomicAdd(&gcur_s[p], hist[p]);
    }
    __syncthreads();
    for (int i = 0; i < CH; i += 256) {
        int ii = i + t;
        if (ii < nitems) {
            int k = base + ii;
            int x = d_rec[k].x;
            int rk = atomicAdd(&cur[(x & 0xFFFF) >> 7], 1);
            sorted[rk] = make_int2(x, k);
        }
    }
    __syncthreads();
    for (int s = t; s < nitems; s += 256) {
        int2 it = sorted[s];
        int p = (it.x & 0xFFFF) >> 7;
        sp1[gbase[p] + (s - loff[p])] = it;
    }
}

// ============================================================
// src-sort pass 2: count-sort by src&127; emits sB[j]=src|r<<16,
// s_k[j]=dst-slot k, offs_s/cnt_s.
// ============================================================
__global__ __launch_bounds__(256) void p2s_kernel(const int* __restrict__ pstart_s,
                                                  const int2* __restrict__ sp1,
                                                  int* __restrict__ sB,
                                                  int* __restrict__ s_k,
                                                  int* __restrict__ offs_s,
                                                  int* __restrict__ cnt_s) {
    __shared__ int2 sorted[CAP];
    __shared__ int h[128], off[128], cur[128], sc[128];
    int p = blockIdx.x;
    int base = pstart_s[p];
    int n = min(pstart_s[p + 1] - base, CAP);
    int t = threadIdx.x;
    if (t < 128) h[t] = 0;
    __syncthreads();
    for (int s = t; s < n; s += 256)
        atomicAdd(&h[sp1[base + s].x & 127], 1);
    __syncthreads();
    if (t < 128) sc[t] = h[t];
    __syncthreads();
    scan128_incl(sc);
    if (t < 128) {
        int lo = t ? sc[t - 1] : 0;
        off[t] = lo;
        cur[t] = lo;
    }
    __syncthreads();
    for (int s = t; s < n; s += 256) {
        int2 it = sp1[base + s];
        int rk = atomicAdd(&cur[it.x & 127], 1);
        sorted[rk] = it;
    }
    __syncthreads();
    for (int s = t; s < n; s += 256) {
        int2 it = sorted[s];
        sB[base + s]  = it.x;
        s_k[base + s] = it.y;
    }
    if (t < 128) {
        int node = (p << 7) + t;
        if (node < NNODES) { offs_s[node] = base + off[t]; cnt_s[node] = h[t]; }
    }
}

// ============================================================
// layer-1 messages: basis1 slices of GS=8 srcs staged in LDS (streaming
// fill), comp1 in LDS; UNNORMALIZED message written at dst-slot k
// (scattered full-64B-line store, fire-and-forget).
// ============================================================
__global__ __launch_bounds__(256) void msg1_lds(const float* __restrict__ basis1,
                                                const float* __restrict__ comp1,
                                                const int* __restrict__ offs_s,
                                                const int* __restrict__ cnt_s,
                                                const int* __restrict__ sB,
                                                const int* __restrict__ s_k,
                                                float* __restrict__ m1) {
    __shared__ float bs[GS * BSTR];
    __shared__ float cs[NREL * NBASIS];
    int src0 = blockIdx.x * GS;
    int t = threadIdx.x;
    for (int i = t; i < (NREL * NBASIS) / 4; i += 256)
        ((float4*)cs)[i] = ((const float4*)comp1)[i];
    for (int i4 = t; i4 < NBASIS * (GS * 4); i4 += 256) {
        int b = i4 >> 5;
        int w = i4 & 31;
        float4 v = ((const float4*)basis1)[(size_t)b * (NNODES * 4) + (size_t)src0 * 4 + w];
        int s = w >> 2;
        int q = w & 3;
        *((float4*)(bs + s * BSTR + b * HDIM) + q) = v;
    }
    __syncthreads();
    int n0 = offs_s[src0];
    int lastS = src0 + GS - 1;
    int n1 = offs_s[lastS] + cnt_s[lastS];
    for (int ii = n0 * 4 + t; ii < n1 * 4; ii += 256) {
        int j = ii >> 2;
        int q = ii & 3;
        int pk = sB[j];
        int k  = s_k[j];
        int src = pk & 0xFFFF;
        int r   = pk >> 16;
        const float* __restrict__ bw = bs + (src - src0) * BSTR + q * 4;
        const float* __restrict__ cp = cs + r * NBASIS;
        float4 acc = make_float4(0.f, 0.f, 0.f, 0.f);
#pragma unroll
        for (int b = 0; b < NBASIS; ++b) {
            float4 bv = *(const float4*)(bw + b * HDIM);
            float  cb = cp[b];
            acc.x = fmaf(cb, bv.x, acc.x);
            acc.y = fmaf(cb, bv.y, acc.y);
            acc.z = fmaf(cb, bv.z, acc.z);
            acc.w = fmaf(cb, bv.w, acc.w);
        }
        ((float4*)m1)[(size_t)k * 4 + q] = acc;
    }
}

// ============================================================
// layer-1 gather: thread per (dst, h-quad); m1 now dst-ordered ->
// fully sequential reads; fuses norm + root1 + bias1 + relu.
// ============================================================
__global__ __launch_bounds__(256) void gather1_flat(const float* __restrict__ m1,
                                                    const float* __restrict__ d_norm,
                                                    const int* __restrict__ offs_d,
                                                    const int* __restrict__ cnt_d,
                                                    const float* __restrict__ root1,
                                                    const float* __restrict__ bias1,
                                                    float* __restrict__ h) {
    int idx = blockIdx.x * blockDim.x + threadIdx.x;
    if (idx >= NNODES * 4) return;
    int dst = idx >> 2;
    int q   = idx & 3;
    int k0 = offs_d[dst];
    int k1 = k0 + cnt_d[dst];
    const float4* __restrict__ mp = (const float4*)m1 + q;
    float4 acc = make_float4(0.f, 0.f, 0.f, 0.f);
    for (int k = k0; k < k1; ++k) {
        float4 v = mp[(size_t)k * 4];
        float nm = d_norm[k];
        acc.x = fmaf(nm, v.x, acc.x);
        acc.y = fmaf(nm, v.y, acc.y);
        acc.z = fmaf(nm, v.z, acc.z);
        acc.w = fmaf(nm, v.w, acc.w);
    }
    float4 rt = ((const float4*)root1)[idx];
    float4 bi = ((const float4*)bias1)[q];
    float4 o;
    o.x = fmaxf(acc.x + rt.x + bi.x, 0.f);
    o.y = fmaxf(acc.y + rt.y + bi.y, 0.f);
    o.z = fmaxf(acc.z + rt.z + bi.z, 0.f);
    o.w = fmaxf(acc.w + rt.w + bi.w, 0.f);
    ((float4*)h)[idx] = o;
}

// ---------------- W2 transposed: w2t[r][c][hh] ; r2t[c][hh] ----------------
__global__ __launch_bounds__(256) void w2_kernel(const float* __restrict__ basis2,
                                                 const float* __restrict__ comp2,
                                                 const float* __restrict__ root2,
                                                 float* __restrict__ w2t,
                                                 float* __restrict__ r2t) {
    int i = blockIdx.x * blockDim.x + threadIdx.x;
    if (i >= NREL * HDIM * NCLS) return;
    int kk = i & (HDIM - 1);
    int c  = (i >> 4) & (NCLS - 1);
    int r  = i >> 7;
    float acc = 0.f;
#pragma unroll
    for (int b = 0; b < NBASIS; ++b)
        acc += comp2[r * NBASIS + b] * basis2[(b * HDIM + kk) * NCLS + c];
    w2t[i] = acc;
    if (i < HDIM * NCLS) {
        int c2 = i >> 4;
        int k2 = i & (HDIM - 1);
        r2t[i] = root2[k2 * NCLS + c2];
    }
}

// ============================================================
// layer-2 messages, edge-parallel: thread per (edge-slot k, class c);
// no serial loop -> latency hidden by TLP. m2[k*8+c] coalesced store.
// ============================================================
__global__ __launch_bounds__(256) void msg2_kernel(const float* __restrict__ h,
                                                   const float* __restrict__ w2t,
                                                   const int2* __restrict__ d_rec,
                                                   const float* __restrict__ d_norm,
                                                   float* __restrict__ m2) {
    int idx = blockIdx.x * blockDim.x + threadIdx.x;   // NEDGE*8 = 6,400,000 exact
    int k = idx >> 3;
    int c = idx & (NCLS - 1);
    int2  rec = d_rec[k];
    float nm  = d_norm[k];
    int src = rec.x & 0xFFFF;
    int r   = rec.x >> 16;
    const float4* __restrict__ hp = (const float4*)h + src * 4;
    const float4* __restrict__ wp = (const float4*)w2t + (r * NCLS + c) * 4;
    float a = 0.f;
#pragma unroll
    for (int qq = 0; qq < 4; ++qq) {
        float4 hv = hp[qq];
        float4 wv = wp[qq];
        a = fmaf(hv.x, wv.x, a);
        a = fmaf(hv.y, wv.y, a);
        a = fmaf(hv.z, wv.z, a);
        a = fmaf(hv.w, wv.w, a);
    }
    m2[idx] = nm * a;
}

// ============================================================
// layer-2 gather: thread per (dst, c); sequential m2 reads;
// fused root2 + bias2 + log_softmax (8-lane shfl).
// ============================================================
__global__ __launch_bounds__(256) void gather2_kernel(const float* __restrict__ m2,
                                                      const float* __restrict__ h,
                                                      const float* __restrict__ r2t,
                                                      const int* __restrict__ offs_d,
                                                      const int* __restrict__ cnt_d,
                                                      const float* __restrict__ bias2,
                                                      float* __restrict__ out) {
    int idx = blockIdx.x * blockDim.x + threadIdx.x;
    if (idx >= NNODES * NCLS) return;
    int dst = idx >> 3;
    int c   = idx & (NCLS - 1);
    int k0 = offs_d[dst];
    int k1 = k0 + cnt_d[dst];
    float acc = 0.f;
    for (int k = k0; k < k1; ++k)
        acc += m2[k * NCLS + c];
    float v = acc + bias2[c];
    const float4* __restrict__ hd = (const float4*)h + dst * 4;
    const float4* __restrict__ rp = (const float4*)r2t + c * 4;
#pragma unroll
    for (int qq = 0; qq < 4; ++qq) {
        float4 hv = hd[qq];
        float4 rv = rp[qq];
        v = fmaf(hv.x, rv.x, v);
        v = fmaf(hv.y, rv.y, v);
        v = fmaf(hv.z, rv.z, v);
        v = fmaf(hv.w, rv.w, v);
    }
    float mx = v;
    mx = fmaxf(mx, __shfl_xor(mx, 1));
    mx = fmaxf(mx, __shfl_xor(mx, 2));
    mx = fmaxf(mx, __shfl_xor(mx, 4));
    float s = expf(v - mx);
    s += __shfl_xor(s, 1);
    s += __shfl_xor(s, 2);
    s += __shfl_xor(s, 4);
    out[idx] = v - mx - logf(s);
}

// ============================================================
// fallback (flat atomic path; needs ~23.3 MB)
// ============================================================
__global__ __launch_bounds__(256) void degcnt_fb(const int* __restrict__ ei,
                                                 const int* __restrict__ et,
                                                 int* __restrict__ deg) {
    int e = blockIdx.x * blockDim.x + threadIdx.x;
    if (e >= NEDGE) return;
    atomicAdd(&deg[ei[NEDGE + e] * NREL + et[e]], 1);
}

__global__ __launch_bounds__(256) void layer1_flat(const int* __restrict__ ei,
                                                   const int* __restrict__ et,
                                                   const float* __restrict__ basis1,
                                                   const float* __restrict__ comp1,
                                                   const int* __restrict__ deg,
                                                   float* __restrict__ h) {
    long long idx = (long long)blockIdx.x * blockDim.x + threadIdx.x;
    if (idx >= (long long)NEDGE * HDIM) return;
    int e  = (int)(idx >> 4);
    int hh = (int)(idx & (HDIM - 1));
    int src = ei[e];
    int dst = ei[NEDGE + e];
    int r   = et[e];
    float norm = 1.0f / (float)deg[dst * NREL + r];
    const float* __restrict__ cp = comp1 + r * NBASIS;
    float acc = 0.f;
#pragma unroll
    for (int b = 0; b < NBASIS; ++b)
        acc += cp[b] * basis1[(b * NNODES + src) * HDIM + hh];
    atomicAdd(&h[dst * HDIM + hh], norm * acc);
}

__global__ __launch_bounds__(256) void relu_kernel(float* __restrict__ h,
                                                   const float* __restrict__ root1,
                                                   const float* __restrict__ bias1) {
    int i = blockIdx.x * blockDim.x + threadIdx.x;
    if (i >= NNODES * HDIM) return;
    float v = h[i] + root1[i] + bias1[i & (HDIM - 1)];
    h[i] = v > 0.f ? v : 0.f;
}

__global__ __launch_bounds__(256) void layer2_flat(const int* __restrict__ ei,
                                                   const int* __restrict__ et,
                                                   const float* __restrict__ h,
                                                   const float* __restrict__ w2t,
                                                   const int* __restrict__ deg,
                                                   float* __restrict__ out_tmp) {
    long long idx = (long long)blockIdx.x * blockDim.x + threadIdx.x;
    if (idx >= (long long)NEDGE * NCLS) return;
    int e = (int)(idx >> 3);
    int c = (int)(idx & (NCLS - 1));
    int src = ei[e];
    int dst = ei[NEDGE + e];
    int r   = et[e];
    float norm = 1.0f / (float)deg[dst * NREL + r];
    const float4* __restrict__ hp = (const float4*)h + src * 4;
    const float4* __restrict__ wp = (const float4*)w2t + (r * NCLS + c) * 4;
    float a = 0.f;
#pragma unroll
    for (int qq = 0; qq < 4; ++qq) {
        float4 hv = hp[qq];
        float4 wv = wp[qq];
        a = fmaf(hv.x, wv.x, a);
        a = fmaf(hv.y, wv.y, a);
        a = fmaf(hv.z, wv.z, a);
        a = fmaf(hv.w, wv.w, a);
    }
    atomicAdd(&out_tmp[dst * NCLS + c], norm * a);
}

__global__ __launch_bounds__(256) void final_kernel(const float* __restrict__ out_tmp,
                                                    const float* __restrict__ h,
                                                    const float* __restrict__ root2,
                                                    const float* __restrict__ bias2,
                                                    float* __restrict__ out) {
    int n = blockIdx.x * blockDim.x + threadIdx.x;
    if (n >= NNODES) return;
    float hv[HDIM];
#pragma unroll
    for (int i = 0; i < HDIM; ++i) hv[i] = h[n * HDIM + i];
    float v[NCLS];
    float mx = -1e30f;
#pragma unroll
    for (int c = 0; c < NCLS; ++c) {
        float acc = out_tmp[n * NCLS + c] + bias2[c];
#pragma unroll
        for (int i = 0; i < HDIM; ++i) acc += hv[i] * root2[i * NCLS + c];
        v[c] = acc;
        mx = fmaxf(mx, acc);
    }
    float s = 0.f;
#pragma unroll
    for (int c = 0; c < NCLS; ++c) s += expf(v[c] - mx);
    float ls = logf(s);
#pragma unroll
    for (int c = 0; c < NCLS; ++c) out[n * NCLS + c] = v[c] - mx - ls;
}

extern "C" void kernel_launch(void* const* d_in, const int* in_sizes, int n_in,
                              void* d_out, int out_size, void* d_ws, size_t ws_size,
                              hipStream_t stream) {
    const int*   ei     = (const int*)d_in[0];
    const int*   et     = (const int*)d_in[1];
    const float* basis1 = (const float*)d_in[2];
    const float* comp1  = (const float*)d_in[3];
    const float* root1  = (const float*)d_in[4];
    const float* bias1  = (const float*)d_in[5];
    const float* basis2 = (const float*)d_in[6];
    const float* comp2  = (const float*)d_in[7];
    const float* root2  = (const float*)d_in[8];
    const float* bias2  = (const float*)d_in[9];
    float* out = (float*)d_out;

    // ---------- primary layout (4-byte words; int2 at even offsets) ----------
    int*   hist_s   = (int*)d_ws;                       // NPART (zero)
    int*   hist_d   = hist_s + NPART;                   // NPART (zero)
    int*   pstart_s = hist_d + NPART;                   // NPART
    int*   pstart_d = pstart_s + NPART;                 // NPART
    int*   gcur_s   = pstart_d + NPART;                 // NPART
    int*   gcur_d   = gcur_s + NPART;                   // NPART -> 2352 words (even)
    int2*  dp1      = (int2*)(gcur_d + NPART);          // E int2 (sp1 aliases after p2d)
    int2*  d_rec    = dp1 + NEDGE;                      // E int2
    int*   sB       = (int*)(d_rec + NEDGE);            // E
    int*   s_k      = sB + NEDGE;                       // E
    float* d_norm   = (float*)(s_k + NEDGE);            // E
    int*   offs_s   = (int*)(d_norm + NEDGE);           // N
    int*   cnt_s    = offs_s + NNODES;                  // N
    int*   offs_d   = cnt_s + NNODES;                   // N
    int*   cnt_d    = offs_d + NNODES;                  // N
    float* m1       = (float*)(cnt_d + NNODES);         // E*H  (offset %4==0 -> 16B aligned)
    float* m2       = m1;                               // E*C aliases m1 (m1 dead after gather1)
    float* h        = m1 + (size_t)NEDGE * HDIM;        // N*H
    float* w2t      = h + (size_t)NNODES * HDIM;        // R*H*C
    float* r2t      = w2t + (size_t)NREL * HDIM * NCLS; // H*C
    int2*  sp1      = dp1;                              // alias: dp1 dead after p2d
    size_t total_words = 6 * (size_t)NPART + 7 * (size_t)NEDGE + 4 * (size_t)NNODES +
                         (size_t)NEDGE * HDIM + (size_t)NNODES * HDIM +
                         (size_t)NREL * HDIM * NCLS + HDIM * NCLS;

    if (ws_size >= total_words * sizeof(float)) {
        hipMemsetAsync(hist_s, 0, 2 * NPART * sizeof(int), stream);
        histp_kernel<<<P1BLK, 256, 0, stream>>>(ei, hist_s, hist_d);
        scanp_kernel<<<2, 256, 0, stream>>>(hist_s, hist_d, pstart_s, pstart_d, gcur_s, gcur_d);
        // dst sort first (raw edges -> k-order)
        p1d_kernel<<<P1BLK, 256, 0, stream>>>(ei, et, gcur_d, dp1);
        p2d_kernel<<<NPART - 1, 256, 0, stream>>>(pstart_d, dp1, d_rec, d_norm, offs_d, cnt_d);
        // src sort of (pk, k) records -> j-order with sequential s_k
        p1s_kernel<<<P1BLK, 256, 0, stream>>>(d_rec, gcur_s, sp1);
        p2s_kernel<<<NPART - 1, 256, 0, stream>>>(pstart_s, sp1, sB, s_k, offs_s, cnt_s);

        msg1_lds<<<NNODES / GS, 256, 0, stream>>>(basis1, comp1, offs_s, cnt_s, sB, s_k, m1);
        gather1_flat<<<(NNODES * 4 + 255) / 256, 256, 0, stream>>>(
            m1, d_norm, offs_d, cnt_d, root1, bias1, h);
        w2_kernel<<<(NREL * HDIM * NCLS + 255) / 256, 256, 0, stream>>>(basis2, comp2, root2,
                                                                        w2t, r2t);
        msg2_kernel<<<(NEDGE * NCLS) / 256, 256, 0, stream>>>(h, w2t, d_rec, d_norm, m2);
        gather2_kernel<<<(NNODES * NCLS + 255) / 256, 256, 0, stream>>>(
            m2, h, r2t, offs_d, cnt_d, bias2, out);
        return;
    }

    // ---------- fallback: flat atomic path (~23.3 MB) ----------
    {
        int*   deg_f   = (int*)d_ws;                               // N*R  (zero)
        float* h_f     = (float*)(deg_f + (size_t)NNODES * NREL);  // N*H  (zero)
        float* out_tmp = h_f + (size_t)NNODES * HDIM;              // N*C  (zero)
        size_t zw = (size_t)NNODES * NREL + NNODES * HDIM + NNODES * NCLS;
        float* w2t_f   = out_tmp + (size_t)NNODES * NCLS;          // R*H*C
        float* r2t_f   = w2t_f + (size_t)NREL * HDIM * NCLS;       // H*C

        hipMemsetAsync(d_ws, 0, zw * sizeof(float), stream);
        degcnt_fb<<<(NEDGE + 255) / 256, 256, 0, stream>>>(ei, et, deg_f);
        layer1_flat<<<((size_t)NEDGE * HDIM + 255) / 256, 256, 0, stream>>>(
            ei, et, basis1, comp1, deg_f, h_f);
        relu_kernel<<<(NNODES * HDIM + 255) / 256, 256, 0, stream>>>(h_f, root1, bias1);
        w2_kernel<<<(NREL * HDIM * NCLS + 255) / 256, 256, 0, stream>>>(basis2, comp2, root2,
                                                                        w2t_f, r2t_f);
        layer2_flat<<<((size_t)NEDGE * NCLS + 255) / 256, 256, 0, stream>>>(
            ei, et, h_f, w2t_f, deg_f, out_tmp);
        final_kernel<<<(NNODES + 255) / 256, 256, 0, stream>>>(out_tmp, h_f, root2, bias2, out);
    }
}

// Round 8
// 193.715 us; speedup vs baseline: 2.0675x; 1.0005x over previous
//
#include <hip/hip_runtime.h>

#define NNODES 50000
#define NREL   90
#define NEDGE  800000
#define HDIM   16
#define NBASIS 30
#define NCLS   8
#define NPART  392    // partitions = node>>7 ; 0..390 used
#define CH     4096   // edges per pass-1 block
#define P1BLK  ((NEDGE + CH - 1) / CH)    // 196
#define CAPSTG 2816   // fixed staging stride per partition (mean 2046, sigma 45)
#define GS     8      // srcs per msg1 block
#define BSTR16 484    // per-src bf16 slice stride (480 + 4)
#define CROW   36     // padded comp1 row stride (floats)

// ---------------- parallel inclusive scans in LDS ----------------
__device__ __forceinline__ void scan512_incl(int* sc) {
    int t = threadIdx.x;
#pragma unroll
    for (int d = 1; d < 512; d <<= 1) {
        int v0 = sc[t];
        int a0 = (t >= d) ? sc[t - d] : 0;
        int v1 = sc[t + 256];
        int a1 = sc[t + 256 - d];
        __syncthreads();
        sc[t] = v0 + a0;
        sc[t + 256] = v1 + a1;
        __syncthreads();
    }
}

__device__ __forceinline__ void scan128_incl(int* sc) {
    int t = threadIdx.x;
#pragma unroll
    for (int d = 1; d < 128; d <<= 1) {
        int v = 0, a = 0;
        if (t < 128) { v = sc[t]; a = (t >= d) ? sc[t - d] : 0; }
        __syncthreads();
        if (t < 128) sc[t] = v + a;
        __syncthreads();
    }
}

// ============================================================
// init cursors: gcur_*[p] = p*CAPSTG ; gcnt = {0,0}
// ============================================================
__global__ __launch_bounds__(256) void initc_kernel(int* __restrict__ gcur_s,
                                                    int* __restrict__ gcur_d,
                                                    int* __restrict__ gcnt) {
    int t = blockIdx.x * 256 + threadIdx.x;
    if (t < NPART) { gcur_s[t] = t * CAPSTG; gcur_d[t] = t * CAPSTG; }
    if (t == NPART) { gcnt[0] = 0; gcnt[1] = 0; }
}

// ============================================================
// dst-sort pass 1: partition raw edges by dst>>7 into fixed-stride staging.
// record: x = src | r<<16 , y = dst. No pre-histogram needed.
// ============================================================
__global__ __launch_bounds__(256) void p1d_kernel(const int* __restrict__ ei,
                                                  const int* __restrict__ et,
                                                  int* __restrict__ gcur_d,
                                                  int2* __restrict__ stg_d) {
    __shared__ int2 sorted[CH];
    __shared__ int hist[NPART], loff[NPART], cur[NPART], gbase[NPART];
    __shared__ int sc[512];
    int base = blockIdx.x * CH;
    int nitems = min(CH, NEDGE - base);
    int t = threadIdx.x;
    for (int i = t; i < NPART; i += 256) hist[i] = 0;
    __syncthreads();
    for (int i = t; i < nitems; i += 256)
        atomicAdd(&hist[ei[NEDGE + base + i] >> 7], 1);
    __syncthreads();
    sc[t]       = (t < NPART) ? hist[t] : 0;
    sc[t + 256] = (t + 256 < NPART) ? hist[t + 256] : 0;
    __syncthreads();
    scan512_incl(sc);
    for (int p = t; p < NPART; p += 256) {
        int lo = p ? sc[p - 1] : 0;
        loff[p] = lo;
        cur[p] = lo;
        if (hist[p]) gbase[p] = atomicAdd(&gcur_d[p], hist[p]);
    }
    __syncthreads();
    for (int i = t; i < nitems; i += 256) {
        int e = base + i;
        int src = ei[e], dst = ei[NEDGE + e], r = et[e];
        int rk = atomicAdd(&cur[dst >> 7], 1);
        sorted[rk] = make_int2(src | (r << 16), dst);
    }
    __syncthreads();
    for (int s = t; s < nitems; s += 256) {
        int2 it = sorted[s];
        int p = it.y >> 7;
        stg_d[gbase[p] + (s - loff[p])] = it;
    }
}

// ============================================================
// dst-sort pass 2 (+ fused src-partition scatter):
//  - count-sort staged items by dst&127
//  - per-edge norm from in-LDS (dst,r) segments
//  - compact emit (one global cursor): d_sr, d_norm, offs_d/cnt_d
//  - group by src>>7 in LDS, reserve staging, coalesced write of (pk, k)
// ============================================================
__global__ __launch_bounds__(256) void p2d_kernel(const int* __restrict__ gcur_d,
                                                  const int2* __restrict__ stg_d,
                                                  int* __restrict__ gcur_s,
                                                  int2* __restrict__ stg_s,
                                                  int* __restrict__ gcnt,
                                                  int* __restrict__ d_sr,
                                                  float* __restrict__ d_norm,
                                                  int* __restrict__ offs_d,
                                                  int* __restrict__ cnt_d) {
    __shared__ int2 sorted[CAPSTG];
    __shared__ int2 sorted2[CAPSTG];
    __shared__ int h[128], off[128], cur[128];
    __shared__ int sc[512];
    __shared__ int shist[NPART], sloff[NPART], scur[NPART], sgbase[NPART];
    __shared__ int kb;
    int p = blockIdx.x;
    int base = p * CAPSTG;
    int n = min(gcur_d[p] - base, CAPSTG);
    int t = threadIdx.x;
    if (t < 128) h[t] = 0;
    __syncthreads();
    for (int s = t; s < n; s += 256)
        atomicAdd(&h[stg_d[base + s].y & 127], 1);
    __syncthreads();
    if (t < 128) sc[t] = h[t];
    __syncthreads();
    scan128_incl(sc);
    if (t < 128) { int lo = t ? sc[t - 1] : 0; off[t] = lo; cur[t] = lo; }
    if (t == 0) kb = atomicAdd(&gcnt[0], n);
    __syncthreads();
    for (int s = t; s < n; s += 256) {
        int2 it = stg_d[base + s];
        int rk = atomicAdd(&cur[it.y & 127], 1);
        sorted[rk] = it;
    }
    __syncthreads();
    int kbase = kb;
    for (int s = t; s < n; s += 256) {
        int2 it = sorted[s];
        int key = it.y & 127;
        int r = it.x >> 16;
        int o = off[key], oe = o + h[key];
        int c = 0;
        for (int kk = o; kk < oe; ++kk)
            c += ((sorted[kk].x >> 16) == r);
        d_sr[kbase + s] = it.x;
        d_norm[kbase + s] = 1.0f / (float)c;
    }
    if (t < 128) {
        int node = (p << 7) + t;
        if (node < NNODES) { offs_d[node] = kbase + off[t]; cnt_d[node] = h[t]; }
    }
    // ---- fused src-partition scatter of (pk, k) ----
    for (int i = t; i < NPART; i += 256) shist[i] = 0;
    __syncthreads();
    for (int s = t; s < n; s += 256)
        atomicAdd(&shist[(sorted[s].x & 0xFFFF) >> 7], 1);
    __syncthreads();
    sc[t]       = (t < NPART) ? shist[t] : 0;
    sc[t + 256] = (t + 256 < NPART) ? shist[t + 256] : 0;
    __syncthreads();
    scan512_incl(sc);
    for (int pp = t; pp < NPART; pp += 256) {
        int lo = pp ? sc[pp - 1] : 0;
        sloff[pp] = lo;
        scur[pp] = lo;
        if (shist[pp]) sgbase[pp] = atomicAdd(&gcur_s[pp], shist[pp]);
    }
    __syncthreads();
    for (int s = t; s < n; s += 256) {
        int2 it = sorted[s];
        int rk = atomicAdd(&scur[(it.x & 0xFFFF) >> 7], 1);
        sorted2[rk] = make_int2(it.x, kbase + s);
    }
    __syncthreads();
    for (int s = t; s < n; s += 256) {
        int2 it = sorted2[s];
        int pp = (it.x & 0xFFFF) >> 7;
        stg_s[sgbase[pp] + (s - sloff[pp])] = it;
    }
}

// ============================================================
// src-sort pass 2: count-sort by src&127; compact emit sB/s_k, offs_s/cnt_s.
// ============================================================
__global__ __launch_bounds__(256) void p2s_kernel(const int* __restrict__ gcur_s,
                                                  const int2* __restrict__ stg_s,
                                                  int* __restrict__ gcnt,
                                                  int* __restrict__ sB,
                                                  int* __restrict__ s_k,
                                                  int* __restrict__ offs_s,
                                                  int* __restrict__ cnt_s) {
    __shared__ int2 sorted[CAPSTG];
    __shared__ int h[128], off[128], cur[128], sc[128];
    __shared__ int jb;
    int p = blockIdx.x;
    int base = p * CAPSTG;
    int n = min(gcur_s[p] - base, CAPSTG);
    int t = threadIdx.x;
    if (t < 128) h[t] = 0;
    __syncthreads();
    for (int s = t; s < n; s += 256)
        atomicAdd(&h[stg_s[base + s].x & 127], 1);
    __syncthreads();
    if (t < 128) sc[t] = h[t];
    __syncthreads();
    scan128_incl(sc);
    if (t < 128) { int lo = t ? sc[t - 1] : 0; off[t] = lo; cur[t] = lo; }
    if (t == 0) jb = atomicAdd(&gcnt[1], n);
    __syncthreads();
    for (int s = t; s < n; s += 256) {
        int2 it = stg_s[base + s];
        int rk = atomicAdd(&cur[it.x & 127], 1);
        sorted[rk] = it;
    }
    __syncthreads();
    int jbase = jb;
    for (int s = t; s < n; s += 256) {
        int2 it = sorted[s];
        sB[jbase + s]  = it.x;
        s_k[jbase + s] = it.y;
    }
    if (t < 128) {
        int node = (p << 7) + t;
        if (node < NNODES) { offs_s[node] = jbase + off[t]; cnt_s[node] = h[t]; }
    }
}

// ============================================================
// layer-1 messages: basis slices of GS=8 srcs in LDS as BF16 (ds_read_b64),
// comp1 row loaded to registers via 8x ds_read_b128 (rows padded to 36 floats).
// Unnormalized bf16 message written at dst-slot k.
// ============================================================
__global__ __launch_bounds__(256) void msg1_lds(const float* __restrict__ basis1,
                                                const float* __restrict__ comp1,
                                                const int* __restrict__ offs_s,
                                                const int* __restrict__ cnt_s,
                                                const int* __restrict__ sB,
                                                const int* __restrict__ s_k,
                                                unsigned int* __restrict__ m1) {
    __shared__ unsigned short bs16[GS * BSTR16];
    __shared__ float cs[NREL * CROW];
    int src0 = blockIdx.x * GS;
    int t = threadIdx.x;
    for (int i = t; i < NREL * NBASIS; i += 256) {
        int r = i / NBASIS;
        int b = i - r * NBASIS;
        cs[r * CROW + b] = comp1[i];
    }
    for (int i4 = t; i4 < NBASIS * 32; i4 += 256) {
        int b = i4 >> 5;
        int w = i4 & 31;
        float4 v = ((const float4*)basis1)[(size_t)b * (NNODES * 4) + (size_t)src0 * 4 + w];
        int s = w >> 2, q = w & 3;
        unsigned u0, u1;
        asm volatile("v_cvt_pk_bf16_f32 %0, %1, %2" : "=v"(u0) : "v"(v.x), "v"(v.y));
        asm volatile("v_cvt_pk_bf16_f32 %0, %1, %2" : "=v"(u1) : "v"(v.z), "v"(v.w));
        *((uint2*)(bs16 + s * BSTR16 + b * 16 + q * 4)) = make_uint2(u0, u1);
    }
    __syncthreads();
    int n0 = offs_s[src0];
    int lastS = src0 + GS - 1;
    int n1 = offs_s[lastS] + cnt_s[lastS];
    for (int ii = n0 * 4 + t; ii < n1 * 4; ii += 256) {
        int j = ii >> 2;
        int q = ii & 3;
        int pk = sB[j];
        int k  = s_k[j];
        int src = pk & 0xFFFF;
        int r   = pk >> 16;
        const unsigned short* bw = bs16 + (src - src0) * BSTR16 + q * 4;
        float4 cc[8];
        const float4* __restrict__ crow = (const float4*)(cs + r * CROW);
#pragma unroll
        for (int m = 0; m < 8; ++m) cc[m] = crow[m];
        float cp[32];
#pragma unroll
        for (int m = 0; m < 8; ++m) {
            cp[4 * m]     = cc[m].x;
            cp[4 * m + 1] = cc[m].y;
            cp[4 * m + 2] = cc[m].z;
            cp[4 * m + 3] = cc[m].w;
        }
        float4 acc = make_float4(0.f, 0.f, 0.f, 0.f);
#pragma unroll
        for (int b = 0; b < NBASIS; ++b) {
            uint2 v = *((const uint2*)(bw + b * 16));
            float f0 = __uint_as_float(v.x << 16);
            float f1 = __uint_as_float(v.x & 0xFFFF0000u);
            float f2 = __uint_as_float(v.y << 16);
            float f3 = __uint_as_float(v.y & 0xFFFF0000u);
            float cb = cp[b];
            acc.x = fmaf(cb, f0, acc.x);
            acc.y = fmaf(cb, f1, acc.y);
            acc.z = fmaf(cb, f2, acc.z);
            acc.w = fmaf(cb, f3, acc.w);
        }
        unsigned u0, u1;
        asm volatile("v_cvt_pk_bf16_f32 %0, %1, %2" : "=v"(u0) : "v"(acc.x), "v"(acc.y));
        asm volatile("v_cvt_pk_bf16_f32 %0, %1, %2" : "=v"(u1) : "v"(acc.z), "v"(acc.w));
        ((uint2*)m1)[(size_t)k * 4 + q] = make_uint2(u0, u1);
    }
}

// ============================================================
// layer-1 gather: thread per (dst, h-quad); m1 bf16, dst-ordered ->
// sequential uint2 reads; fuses norm + root1 + bias1 + relu.
// ============================================================
__global__ __launch_bounds__(256) void gather1_flat(const unsigned int* __restrict__ m1,
                                                    const float* __restrict__ d_norm,
                                                    const int* __restrict__ offs_d,
                                                    const int* __restrict__ cnt_d,
                                                    const float* __restrict__ root1,
                                                    const float* __restrict__ bias1,
                                                    float* __restrict__ h) {
    int idx = blockIdx.x * blockDim.x + threadIdx.x;
    if (idx >= NNODES * 4) return;
    int dst = idx >> 2;
    int q   = idx & 3;
    int k0 = offs_d[dst];
    int k1 = k0 + cnt_d[dst];
    float4 acc = make_float4(0.f, 0.f, 0.f, 0.f);
    for (int k = k0; k < k1; ++k) {
        uint2 v = ((const uint2*)m1)[(size_t)k * 4 + q];
        float nm = d_norm[k];
        acc.x = fmaf(nm, __uint_as_float(v.x << 16), acc.x);
        acc.y = fmaf(nm, __uint_as_float(v.x & 0xFFFF0000u), acc.y);
        acc.z = fmaf(nm, __uint_as_float(v.y << 16), acc.z);
        acc.w = fmaf(nm, __uint_as_float(v.y & 0xFFFF0000u), acc.w);
    }
    float4 rt = ((const float4*)root1)[idx];
    float4 bi = ((const float4*)bias1)[q];
    float4 o;
    o.x = fmaxf(acc.x + rt.x + bi.x, 0.f);
    o.y = fmaxf(acc.y + rt.y + bi.y, 0.f);
    o.z = fmaxf(acc.z + rt.z + bi.z, 0.f);
    o.w = fmaxf(acc.w + rt.w + bi.w, 0.f);
    ((float4*)h)[idx] = o;
}

// ---------------- W2 transposed: w2t[r][c][hh] ; r2t[c][hh] ----------------
__global__ __launch_bounds__(256) void w2_kernel(const float* __restrict__ basis2,
                                                 const float* __restrict__ comp2,
                                                 const float* __restrict__ root2,
                                                 float* __restrict__ w2t,
                                                 float* __restrict__ r2t) {
    int i = blockIdx.x * blockDim.x + threadIdx.x;
    if (i >= NREL * HDIM * NCLS) return;
    int kk = i & (HDIM - 1);
    int c  = (i >> 4) & (NCLS - 1);
    int r  = i >> 7;
    float acc = 0.f;
#pragma unroll
    for (int b = 0; b < NBASIS; ++b)
        acc += comp2[r * NBASIS + b] * basis2[(b * HDIM + kk) * NCLS + c];
    w2t[i] = acc;
    if (i < HDIM * NCLS) {
        int c2 = i >> 4;
        int k2 = i & (HDIM - 1);
        r2t[i] = root2[k2 * NCLS + c2];
    }
}

// ============================================================
// layer-2 messages, edge-parallel: thread per (edge-slot k, class c).
// ============================================================
__global__ __launch_bounds__(256) void msg2_kernel(const float* __restrict__ h,
                                                   const float* __restrict__ w2t,
                                                   const int* __restrict__ d_sr,
                                                   const float* __restrict__ d_norm,
                                                   float* __restrict__ m2) {
    int idx = blockIdx.x * blockDim.x + threadIdx.x;   // NEDGE*8 exact
    int k = idx >> 3;
    int c = idx & (NCLS - 1);
    int pk = d_sr[k];
    float nm = d_norm[k];
    int src = pk & 0xFFFF;
    int r   = pk >> 16;
    const float4* __restrict__ hp = (const float4*)h + src * 4;
    const float4* __restrict__ wp = (const float4*)w2t + (r * NCLS + c) * 4;
    float a = 0.f;
#pragma unroll
    for (int qq = 0; qq < 4; ++qq) {
        float4 hv = hp[qq];
        float4 wv = wp[qq];
        a = fmaf(hv.x, wv.x, a);
        a = fmaf(hv.y, wv.y, a);
        a = fmaf(hv.z, wv.z, a);
        a = fmaf(hv.w, wv.w, a);
    }
    m2[idx] = nm * a;
}

// ============================================================
// layer-2 gather: thread per (dst, c); sequential m2 reads;
// fused root2 + bias2 + log_softmax (8-lane shfl).
// ============================================================
__global__ __launch_bounds__(256) void gather2_kernel(const float* __restrict__ m2,
                                                      const float* __restrict__ h,
                                                      const float* __restrict__ r2t,
                                                      const int* __restrict__ offs_d,
                                                      const int* __restrict__ cnt_d,
                                                      const float* __restrict__ bias2,
                                                      float* __restrict__ out) {
    int idx = blockIdx.x * blockDim.x + threadIdx.x;
    if (idx >= NNODES * NCLS) return;
    int dst = idx >> 3;
    int c   = idx & (NCLS - 1);
    int k0 = offs_d[dst];
    int k1 = k0 + cnt_d[dst];
    float acc = 0.f;
    for (int k = k0; k < k1; ++k)
        acc += m2[k * NCLS + c];
    float v = acc + bias2[c];
    const float4* __restrict__ hd = (const float4*)h + dst * 4;
    const float4* __restrict__ rp = (const float4*)r2t + c * 4;
#pragma unroll
    for (int qq = 0; qq < 4; ++qq) {
        float4 hv = hd[qq];
        float4 rv = rp[qq];
        v = fmaf(hv.x, rv.x, v);
        v = fmaf(hv.y, rv.y, v);
        v = fmaf(hv.z, rv.z, v);
        v = fmaf(hv.w, rv.w, v);
    }
    float mx = v;
    mx = fmaxf(mx, __shfl_xor(mx, 1));
    mx = fmaxf(mx, __shfl_xor(mx, 2));
    mx = fmaxf(mx, __shfl_xor(mx, 4));
    float s = expf(v - mx);
    s += __shfl_xor(s, 1);
    s += __shfl_xor(s, 2);
    s += __shfl_xor(s, 4);
    out[idx] = v - mx - logf(s);
}

// ============================================================
// fallback (flat atomic path; needs ~23.3 MB)
// ============================================================
__global__ __launch_bounds__(256) void degcnt_fb(const int* __restrict__ ei,
                                                 const int* __restrict__ et,
                                                 int* __restrict__ deg) {
    int e = blockIdx.x * blockDim.x + threadIdx.x;
    if (e >= NEDGE) return;
    atomicAdd(&deg[ei[NEDGE + e] * NREL + et[e]], 1);
}

__global__ __launch_bounds__(256) void layer1_flat(const int* __restrict__ ei,
                                                   const int* __restrict__ et,
                                                   const float* __restrict__ basis1,
                                                   const float* __restrict__ comp1,
                                                   const int* __restrict__ deg,
                                                   float* __restrict__ h) {
    long long idx = (long long)blockIdx.x * blockDim.x + threadIdx.x;
    if (idx >= (long long)NEDGE * HDIM) return;
    int e  = (int)(idx >> 4);
    int hh = (int)(idx & (HDIM - 1));
    int src = ei[e];
    int dst = ei[NEDGE + e];
    int r   = et[e];
    float norm = 1.0f / (float)deg[dst * NREL + r];
    const float* __restrict__ cp = comp1 + r * NBASIS;
    float acc = 0.f;
#pragma unroll
    for (int b = 0; b < NBASIS; ++b)
        acc += cp[b] * basis1[(b * NNODES + src) * HDIM + hh];
    atomicAdd(&h[dst * HDIM + hh], norm * acc);
}

__global__ __launch_bounds__(256) void relu_kernel(float* __restrict__ h,
                                                   const float* __restrict__ root1,
                                                   const float* __restrict__ bias1) {
    int i = blockIdx.x * blockDim.x + threadIdx.x;
    if (i >= NNODES * HDIM) return;
    float v = h[i] + root1[i] + bias1[i & (HDIM - 1)];
    h[i] = v > 0.f ? v : 0.f;
}

__global__ __launch_bounds__(256) void layer2_flat(const int* __restrict__ ei,
                                                   const int* __restrict__ et,
                                                   const float* __restrict__ h,
                                                   const float* __restrict__ w2t,
                                                   const int* __restrict__ deg,
                                                   float* __restrict__ out_tmp) {
    long long idx = (long long)blockIdx.x * blockDim.x + threadIdx.x;
    if (idx >= (long long)NEDGE * NCLS) return;
    int e = (int)(idx >> 3);
    int c = (int)(idx & (NCLS - 1));
    int src = ei[e];
    int dst = ei[NEDGE + e];
    int r   = et[e];
    float norm = 1.0f / (float)deg[dst * NREL + r];
    const float4* __restrict__ hp = (const float4*)h + src * 4;
    const float4* __restrict__ wp = (const float4*)w2t + (r * NCLS + c) * 4;
    float a = 0.f;
#pragma unroll
    for (int qq = 0; qq < 4; ++qq) {
        float4 hv = hp[qq];
        float4 wv = wp[qq];
        a = fmaf(hv.x, wv.x, a);
        a = fmaf(hv.y, wv.y, a);
        a = fmaf(hv.z, wv.z, a);
        a = fmaf(hv.w, wv.w, a);
    }
    atomicAdd(&out_tmp[dst * NCLS + c], norm * a);
}

__global__ __launch_bounds__(256) void final_kernel(const float* __restrict__ out_tmp,
                                                    const float* __restrict__ h,
                                                    const float* __restrict__ root2,
                                                    const float* __restrict__ bias2,
                                                    float* __restrict__ out) {
    int n = blockIdx.x * blockDim.x + threadIdx.x;
    if (n >= NNODES) return;
    float hv[HDIM];
#pragma unroll
    for (int i = 0; i < HDIM; ++i) hv[i] = h[n * HDIM + i];
    float v[NCLS];
    float mx = -1e30f;
#pragma unroll
    for (int c = 0; c < NCLS; ++c) {
        float acc = out_tmp[n * NCLS + c] + bias2[c];
#pragma unroll
        for (int i = 0; i < HDIM; ++i) acc += hv[i] * root2[i * NCLS + c];
        v[c] = acc;
        mx = fmaxf(mx, acc);
    }
    float s = 0.f;
#pragma unroll
    for (int c = 0; c < NCLS; ++c) s += expf(v[c] - mx);
    float ls = logf(s);
#pragma unroll
    for (int c = 0; c < NCLS; ++c) out[n * NCLS + c] = v[c] - mx - ls;
}

extern "C" void kernel_launch(void* const* d_in, const int* in_sizes, int n_in,
                              void* d_out, int out_size, void* d_ws, size_t ws_size,
                              hipStream_t stream) {
    const int*   ei     = (const int*)d_in[0];
    const int*   et     = (const int*)d_in[1];
    const float* basis1 = (const float*)d_in[2];
    const float* comp1  = (const float*)d_in[3];
    const float* root1  = (const float*)d_in[4];
    const float* bias1  = (const float*)d_in[5];
    const float* basis2 = (const float*)d_in[6];
    const float* comp2  = (const float*)d_in[7];
    const float* root2  = (const float*)d_in[8];
    const float* bias2  = (const float*)d_in[9];
    float* out = (float*)d_out;

    // ---------- primary layout (4-byte words; int2/uint2 at even offsets) ----------
    int*   gcur_s = (int*)d_ws;                             // NPART
    int*   gcur_d = gcur_s + NPART;                         // NPART
    int*   gcnt   = gcur_d + NPART;                         // 4 -> 788 words (even)
    int2*  stg_d  = (int2*)(gcnt + 4);                      // NPART*CAPSTG int2
    int2*  stg_s  = stg_d + (size_t)NPART * CAPSTG;         // NPART*CAPSTG int2
    int*   d_sr   = (int*)(stg_s + (size_t)NPART * CAPSTG); // E
    float* d_norm = (float*)(d_sr + NEDGE);                 // E
    int*   sB     = (int*)(d_norm + NEDGE);                 // E
    int*   s_k    = sB + NEDGE;                             // E
    int*   offs_s = s_k + NEDGE;                            // N
    int*   cnt_s  = offs_s + NNODES;                        // N
    int*   offs_d = cnt_s + NNODES;                         // N
    int*   cnt_d  = offs_d + NNODES;                        // N
    unsigned int* m1 = (unsigned int*)(cnt_d + NNODES);     // E*8 words (E*16 bf16)
    float* m2     = (float*)m1;                             // E*8 f32 aliases (m1 dead)
    float* h      = (float*)(m1 + (size_t)NEDGE * 8);       // N*H
    float* w2t    = h + (size_t)NNODES * HDIM;              // R*H*C
    float* r2t    = w2t + (size_t)NREL * HDIM * NCLS;       // H*C
    size_t total_words = 2 * (size_t)NPART + 4 +
                         4 * (size_t)NPART * CAPSTG +
                         4 * (size_t)NEDGE + 4 * (size_t)NNODES +
                         (size_t)NEDGE * 8 + (size_t)NNODES * HDIM +
                         (size_t)NREL * HDIM * NCLS + HDIM * NCLS;

    if (ws_size >= total_words * sizeof(float)) {
        initc_kernel<<<2, 256, 0, stream>>>(gcur_s, gcur_d, gcnt);
        p1d_kernel<<<P1BLK, 256, 0, stream>>>(ei, et, gcur_d, stg_d);
        p2d_kernel<<<NPART - 1, 256, 0, stream>>>(gcur_d, stg_d, gcur_s, stg_s, gcnt,
                                                  d_sr, d_norm, offs_d, cnt_d);
        p2s_kernel<<<NPART - 1, 256, 0, stream>>>(gcur_s, stg_s, gcnt, sB, s_k, offs_s, cnt_s);

        msg1_lds<<<NNODES / GS, 256, 0, stream>>>(basis1, comp1, offs_s, cnt_s, sB, s_k, m1);
        gather1_flat<<<(NNODES * 4 + 255) / 256, 256, 0, stream>>>(
            m1, d_norm, offs_d, cnt_d, root1, bias1, h);
        w2_kernel<<<(NREL * HDIM * NCLS + 255) / 256, 256, 0, stream>>>(basis2, comp2, root2,
                                                                        w2t, r2t);
        msg2_kernel<<<(NEDGE * NCLS) / 256, 256, 0, stream>>>(h, w2t, d_sr, d_norm, m2);
        gather2_kernel<<<(NNODES * NCLS + 255) / 256, 256, 0, stream>>>(
            m2, h, r2t, offs_d, cnt_d, bias2, out);
        return;
    }

    // ---------- fallback: flat atomic path (~23.3 MB) ----------
    {
        int*   deg_f   = (int*)d_ws;                               // N*R  (zero)
        float* h_f     = (float*)(deg_f + (size_t)NNODES * NREL);  // N*H  (zero)
        float* out_tmp = h_f + (size_t)NNODES * HDIM;              // N*C  (zero)
        size_t zw = (size_t)NNODES * NREL + NNODES * HDIM + NNODES * NCLS;
        float* w2t_f   = out_tmp + (size_t)NNODES * NCLS;          // R*H*C
        float* r2t_f   = w2t_f + (size_t)NREL * HDIM * NCLS;       // H*C

        hipMemsetAsync(d_ws, 0, zw * sizeof(float), stream);
        degcnt_fb<<<(NEDGE + 255) / 256, 256, 0, stream>>>(ei, et, deg_f);
        layer1_flat<<<((size_t)NEDGE * HDIM + 255) / 256, 256, 0, stream>>>(
            ei, et, basis1, comp1, deg_f, h_f);
        relu_kernel<<<(NNODES * HDIM + 255) / 256, 256, 0, stream>>>(h_f, root1, bias1);
        w2_kernel<<<(NREL * HDIM * NCLS + 255) / 256, 256, 0, stream>>>(basis2, comp2, root2,
                                                                        w2t_f, r2t_f);
        layer2_flat<<<((size_t)NEDGE * NCLS + 255) / 256, 256, 0, stream>>>(
            ei, et, h_f, w2t_f, deg_f, out_tmp);
        final_kernel<<<(NNODES + 255) / 256, 256, 0, stream>>>(out_tmp, h_f, root2, bias2, out);
    }
}

// Round 10
// 173.324 us; speedup vs baseline: 2.3107x; 1.1177x over previous
//
#include <hip/hip_runtime.h>

#define NNODES 50000
#define NREL   90
#define NEDGE  800000
#define HDIM   16
#define NBASIS 30
#define NCLS   8
#define NPART  392    // partitions = node>>7 ; 0..390 used
#define CH     4096   // edges per pass-1 block
#define P1BLK  ((NEDGE + CH - 1) / CH)    // 196
#define CAPSTG 2816   // fixed staging stride per partition (mean 2046, sigma 45)
#define GS     8      // srcs per msg1 block
#define BSTR2  260    // per-src packed slice stride in u32 (15*16=240 + pad; %4==0)
#define CROW2  20     // packed comp row stride in u32 (15 + pad; %4==0 -> 16B aligned)

typedef __fp16 h2 __attribute__((ext_vector_type(2)));

static __device__ __forceinline__ unsigned pk2(float a, float b) {
    h2 p = __builtin_amdgcn_cvt_pkrtz(a, b);
    return __builtin_bit_cast(unsigned, p);
}
static __device__ __forceinline__ h2 uph(unsigned u) {
    return __builtin_bit_cast(h2, u);
}
static __device__ __forceinline__ float fd2(unsigned a, unsigned b, float c) {
#if __has_builtin(__builtin_amdgcn_fdot2)
    return __builtin_amdgcn_fdot2(uph(a), uph(b), c, false);
#else
    h2 x = uph(a), y = uph(b);
    return fmaf((float)x.y, (float)y.y, fmaf((float)x.x, (float)y.x, c));
#endif
}

// ---------------- parallel inclusive scans in LDS ----------------
__device__ __forceinline__ void scan512_incl(int* sc) {
    int t = threadIdx.x;
#pragma unroll
    for (int d = 1; d < 512; d <<= 1) {
        int v0 = sc[t];
        int a0 = (t >= d) ? sc[t - d] : 0;
        int v1 = sc[t + 256];
        int a1 = sc[t + 256 - d];
        __syncthreads();
        sc[t] = v0 + a0;
        sc[t + 256] = v1 + a1;
        __syncthreads();
    }
}

__device__ __forceinline__ void scan128_incl(int* sc) {
    int t = threadIdx.x;
#pragma unroll
    for (int d = 1; d < 128; d <<= 1) {
        int v = 0, a = 0;
        if (t < 128) { v = sc[t]; a = (t >= d) ? sc[t - d] : 0; }
        __syncthreads();
        if (t < 128) sc[t] = v + a;
        __syncthreads();
    }
}

// ============================================================
// init: cursors, gcnt, and pre-packed f16 comp1 rows (r*CROW2 + b2)
// ============================================================
__global__ __launch_bounds__(256) void initc_kernel(int* __restrict__ gcur_s,
                                                    int* __restrict__ gcur_d,
                                                    int* __restrict__ gcnt,
                                                    const float* __restrict__ comp1,
                                                    unsigned* __restrict__ comp_pk) {
    int t = blockIdx.x * 256 + threadIdx.x;
    if (t < NPART) { gcur_s[t] = t * CAPSTG; gcur_d[t] = t * CAPSTG; }
    else if (t == NPART) { gcnt[0] = 0; gcnt[1] = 0; }
    int i = t - 512;
    if (i >= 0 && i < NREL * 15) {
        int r = i / 15;
        int b2 = i - r * 15;
        comp_pk[r * CROW2 + b2] = pk2(comp1[r * NBASIS + 2 * b2],
                                      comp1[r * NBASIS + 2 * b2 + 1]);
    }
    // zero the padding words so reads are defined (never used in math)
    if (i >= NREL * 15 && i < NREL * 15 + NREL * (CROW2 - 15)) {
        int j = i - NREL * 15;
        int r = j / (CROW2 - 15);
        int pcol = 15 + (j - r * (CROW2 - 15));
        comp_pk[r * CROW2 + pcol] = 0;
    }
}

// ============================================================
// dst-sort pass 1: partition raw edges by dst>>7 into fixed-stride staging.
// ============================================================
__global__ __launch_bounds__(256) void p1d_kernel(const int* __restrict__ ei,
                                                  const int* __restrict__ et,
                                                  int* __restrict__ gcur_d,
                                                  int2* __restrict__ stg_d) {
    __shared__ int2 sorted[CH];
    __shared__ int hist[NPART], loff[NPART], cur[NPART], gbase[NPART];
    __shared__ int sc[512];
    int base = blockIdx.x * CH;
    int nitems = min(CH, NEDGE - base);
    int t = threadIdx.x;
    for (int i = t; i < NPART; i += 256) hist[i] = 0;
    __syncthreads();
    for (int i = t; i < nitems; i += 256)
        atomicAdd(&hist[ei[NEDGE + base + i] >> 7], 1);
    __syncthreads();
    sc[t]       = (t < NPART) ? hist[t] : 0;
    sc[t + 256] = (t + 256 < NPART) ? hist[t + 256] : 0;
    __syncthreads();
    scan512_incl(sc);
    for (int p = t; p < NPART; p += 256) {
        int lo = p ? sc[p - 1] : 0;
        loff[p] = lo;
        cur[p] = lo;
        if (hist[p]) gbase[p] = atomicAdd(&gcur_d[p], hist[p]);
    }
    __syncthreads();
    for (int i = t; i < nitems; i += 256) {
        int e = base + i;
        int src = ei[e], dst = ei[NEDGE + e], r = et[e];
        int rk = atomicAdd(&cur[dst >> 7], 1);
        sorted[rk] = make_int2(src | (r << 16), dst);
    }
    __syncthreads();
    for (int s = t; s < nitems; s += 256) {
        int2 it = sorted[s];
        int p = it.y >> 7;
        stg_d[gbase[p] + (s - loff[p])] = it;
    }
}

// ============================================================
// dst-sort pass 2 (+ fused src-partition scatter)
// ============================================================
__global__ __launch_bounds__(256) void p2d_kernel(const int* __restrict__ gcur_d,
                                                  const int2* __restrict__ stg_d,
                                                  int* __restrict__ gcur_s,
                                                  int2* __restrict__ stg_s,
                                                  int* __restrict__ gcnt,
                                                  int* __restrict__ d_sr,
                                                  float* __restrict__ d_norm,
                                                  int* __restrict__ offs_d,
                                                  int* __restrict__ cnt_d) {
    __shared__ int2 sorted[CAPSTG];
    __shared__ int2 sorted2[CAPSTG];
    __shared__ int h[128], off[128], cur[128];
    __shared__ int sc[512];
    __shared__ int shist[NPART], sloff[NPART], scur[NPART], sgbase[NPART];
    __shared__ int kb;
    int p = blockIdx.x;
    int base = p * CAPSTG;
    int n = min(gcur_d[p] - base, CAPSTG);
    int t = threadIdx.x;
    if (t < 128) h[t] = 0;
    __syncthreads();
    for (int s = t; s < n; s += 256)
        atomicAdd(&h[stg_d[base + s].y & 127], 1);
    __syncthreads();
    if (t < 128) sc[t] = h[t];
    __syncthreads();
    scan128_incl(sc);
    if (t < 128) { int lo = t ? sc[t - 1] : 0; off[t] = lo; cur[t] = lo; }
    if (t == 0) kb = atomicAdd(&gcnt[0], n);
    __syncthreads();
    for (int s = t; s < n; s += 256) {
        int2 it = stg_d[base + s];
        int rk = atomicAdd(&cur[it.y & 127], 1);
        sorted[rk] = it;
    }
    __syncthreads();
    int kbase = kb;
    for (int s = t; s < n; s += 256) {
        int2 it = sorted[s];
        int key = it.y & 127;
        int r = it.x >> 16;
        int o = off[key], oe = o + h[key];
        int c = 0;
        for (int kk = o; kk < oe; ++kk)
            c += ((sorted[kk].x >> 16) == r);
        d_sr[kbase + s] = it.x;
        d_norm[kbase + s] = 1.0f / (float)c;
    }
    if (t < 128) {
        int node = (p << 7) + t;
        if (node < NNODES) { offs_d[node] = kbase + off[t]; cnt_d[node] = h[t]; }
    }
    // ---- fused src-partition scatter of (pk, k) ----
    for (int i = t; i < NPART; i += 256) shist[i] = 0;
    __syncthreads();
    for (int s = t; s < n; s += 256)
        atomicAdd(&shist[(sorted[s].x & 0xFFFF) >> 7], 1);
    __syncthreads();
    sc[t]       = (t < NPART) ? shist[t] : 0;
    sc[t + 256] = (t + 256 < NPART) ? shist[t + 256] : 0;
    __syncthreads();
    scan512_incl(sc);
    for (int pp = t; pp < NPART; pp += 256) {
        int lo = pp ? sc[pp - 1] : 0;
        sloff[pp] = lo;
        scur[pp] = lo;
        if (shist[pp]) sgbase[pp] = atomicAdd(&gcur_s[pp], shist[pp]);
    }
    __syncthreads();
    for (int s = t; s < n; s += 256) {
        int2 it = sorted[s];
        int rk = atomicAdd(&scur[(it.x & 0xFFFF) >> 7], 1);
        sorted2[rk] = make_int2(it.x, kbase + s);
    }
    __syncthreads();
    for (int s = t; s < n; s += 256) {
        int2 it = sorted2[s];
        int pp = (it.x & 0xFFFF) >> 7;
        stg_s[sgbase[pp] + (s - sloff[pp])] = it;
    }
}

// ============================================================
// src-sort pass 2: count-sort by src&127; emits sB/s_k, offs_s/cnt_s.
// ============================================================
__global__ __launch_bounds__(256) void p2s_kernel(const int* __restrict__ gcur_s,
                                                  const int2* __restrict__ stg_s,
                                                  int* __restrict__ gcnt,
                                                  int* __restrict__ sB,
                                                  int* __restrict__ s_k,
                                                  int* __restrict__ offs_s,
                                                  int* __restrict__ cnt_s) {
    __shared__ int2 sorted[CAPSTG];
    __shared__ int h[128], off[128], cur[128], sc[128];
    __shared__ int jb;
    int p = blockIdx.x;
    int base = p * CAPSTG;
    int n = min(gcur_s[p] - base, CAPSTG);
    int t = threadIdx.x;
    if (t < 128) h[t] = 0;
    __syncthreads();
    for (int s = t; s < n; s += 256)
        atomicAdd(&h[stg_s[base + s].x & 127], 1);
    __syncthreads();
    if (t < 128) sc[t] = h[t];
    __syncthreads();
    scan128_incl(sc);
    if (t < 128) { int lo = t ? sc[t - 1] : 0; off[t] = lo; cur[t] = lo; }
    if (t == 0) jb = atomicAdd(&gcnt[1], n);
    __syncthreads();
    for (int s = t; s < n; s += 256) {
        int2 it = stg_s[base + s];
        int rk = atomicAdd(&cur[it.x & 127], 1);
        sorted[rk] = it;
    }
    __syncthreads();
    int jbase = jb;
    for (int s = t; s < n; s += 256) {
        int2 it = sorted[s];
        sB[jbase + s]  = it.x;
        s_k[jbase + s] = it.y;
    }
    if (t < 128) {
        int node = (p << 7) + t;
        if (node < NNODES) { offs_s[node] = jbase + off[t]; cnt_s[node] = h[t]; }
    }
}

// ============================================================
// layer-1 messages: basis slices packed as f16 PAIRS OVER b in LDS
// (bs_pk[s][b2][h] u32). Inner loop = 15 ds_read_b128 + 60 v_dot2_f32_f16
// per (edge, h-quad): no unpack VALU. comp rows pre-packed (4 b128 -> regs).
// f16 message written at dst-slot k.
// ============================================================
__global__ __launch_bounds__(256) void msg1_lds(const float* __restrict__ basis1,
                                                const unsigned* __restrict__ comp_pk,
                                                const int* __restrict__ offs_s,
                                                const int* __restrict__ cnt_s,
                                                const int* __restrict__ sB,
                                                const int* __restrict__ s_k,
                                                unsigned* __restrict__ m1) {
    __shared__ unsigned bspk[GS * BSTR2];     // 8.3 KB
    __shared__ unsigned cpk[NREL * CROW2];    // 7.2 KB
    int src0 = blockIdx.x * GS;
    int t = threadIdx.x;
    for (int i = t; i < NREL * CROW2; i += 256)
        cpk[i] = comp_pk[i];
    // pack basis rows 2*b2, 2*b2+1 -> u32 pairs; 15*32 float4-pair units
    for (int i4 = t; i4 < 15 * 32; i4 += 256) {
        int b2 = i4 >> 5;
        int w  = i4 & 31;
        const float4* bp = (const float4*)basis1;
        float4 a = bp[(size_t)(2 * b2)     * (NNODES * 4) + (size_t)src0 * 4 + w];
        float4 b = bp[(size_t)(2 * b2 + 1) * (NNODES * 4) + (size_t)src0 * 4 + w];
        int s = w >> 2, q = w & 3;
        uint4 o;
        o.x = pk2(a.x, b.x);
        o.y = pk2(a.y, b.y);
        o.z = pk2(a.z, b.z);
        o.w = pk2(a.w, b.w);
        *((uint4*)(bspk + s * BSTR2 + b2 * 16 + q * 4)) = o;
    }
    __syncthreads();
    int n0 = offs_s[src0];
    int lastS = src0 + GS - 1;
    int n1 = offs_s[lastS] + cnt_s[lastS];
    for (int ii = n0 * 4 + t; ii < n1 * 4; ii += 256) {
        int j = ii >> 2;
        int q = ii & 3;
        int pk = sB[j];
        int k  = s_k[j];
        int src = pk & 0xFFFF;
        int r   = pk >> 16;
        const uint4* crow = (const uint4*)(cpk + r * CROW2);
        uint4 c0 = crow[0], c1 = crow[1], c2 = crow[2], c3 = crow[3];
        const unsigned* bw = bspk + (src - src0) * BSTR2 + q * 4;
        float a0 = 0.f, a1 = 0.f, a2 = 0.f, a3 = 0.f;
#define MSG1_STEP(B2, CB) { \
        uint4 v = *((const uint4*)(bw + (B2) * 16)); \
        a0 = fd2(v.x, (CB), a0); \
        a1 = fd2(v.y, (CB), a1); \
        a2 = fd2(v.z, (CB), a2); \
        a3 = fd2(v.w, (CB), a3); }
        MSG1_STEP(0,  c0.x) MSG1_STEP(1,  c0.y) MSG1_STEP(2,  c0.z) MSG1_STEP(3,  c0.w)
        MSG1_STEP(4,  c1.x) MSG1_STEP(5,  c1.y) MSG1_STEP(6,  c1.z) MSG1_STEP(7,  c1.w)
        MSG1_STEP(8,  c2.x) MSG1_STEP(9,  c2.y) MSG1_STEP(10, c2.z) MSG1_STEP(11, c2.w)
        MSG1_STEP(12, c3.x) MSG1_STEP(13, c3.y) MSG1_STEP(14, c3.z)
#undef MSG1_STEP
        ((uint2*)m1)[(size_t)k * 4 + q] = make_uint2(pk2(a0, a1), pk2(a2, a3));
    }
}

// ============================================================
// layer-1 gather: thread per (dst, h-quad); m1 f16, dst-ordered ->
// sequential uint2 reads; fuses norm + root1 + bias1 + relu.
// ============================================================
__global__ __launch_bounds__(256) void gather1_flat(const unsigned* __restrict__ m1,
                                                    const float* __restrict__ d_norm,
                                                    const int* __restrict__ offs_d,
                                                    const int* __restrict__ cnt_d,
                                                    const float* __restrict__ root1,
                                                    const float* __restrict__ bias1,
                                                    float* __restrict__ h) {
    int idx = blockIdx.x * blockDim.x + threadIdx.x;
    if (idx >= NNODES * 4) return;
    int dst = idx >> 2;
    int q   = idx & 3;
    int k0 = offs_d[dst];
    int k1 = k0 + cnt_d[dst];
    float4 acc = make_float4(0.f, 0.f, 0.f, 0.f);
    for (int k = k0; k < k1; ++k) {
        uint2 v = ((const uint2*)m1)[(size_t)k * 4 + q];
        float nm = d_norm[k];
        h2 x = uph(v.x), y = uph(v.y);
        acc.x = fmaf(nm, (float)x.x, acc.x);
        acc.y = fmaf(nm, (float)x.y, acc.y);
        acc.z = fmaf(nm, (float)y.x, acc.z);
        acc.w = fmaf(nm, (float)y.y, acc.w);
    }
    float4 rt = ((const float4*)root1)[idx];
    float4 bi = ((const float4*)bias1)[q];
    float4 o;
    o.x = fmaxf(acc.x + rt.x + bi.x, 0.f);
    o.y = fmaxf(acc.y + rt.y + bi.y, 0.f);
    o.z = fmaxf(acc.z + rt.z + bi.z, 0.f);
    o.w = fmaxf(acc.w + rt.w + bi.w, 0.f);
    ((float4*)h)[idx] = o;
}

// ---------------- W2 transposed: w2t[r][c][hh] ; r2t[c][hh] ----------------
__global__ __launch_bounds__(256) void w2_kernel(const float* __restrict__ basis2,
                                                 const float* __restrict__ comp2,
                                                 const float* __restrict__ root2,
                                                 float* __restrict__ w2t,
                                                 float* __restrict__ r2t) {
    int i = blockIdx.x * blockDim.x + threadIdx.x;
    if (i >= NREL * HDIM * NCLS) return;
    int kk = i & (HDIM - 1);
    int c  = (i >> 4) & (NCLS - 1);
    int r  = i >> 7;
    float acc = 0.f;
#pragma unroll
    for (int b = 0; b < NBASIS; ++b)
        acc += comp2[r * NBASIS + b] * basis2[(b * HDIM + kk) * NCLS + c];
    w2t[i] = acc;
    if (i < HDIM * NCLS) {
        int c2 = i >> 4;
        int k2 = i & (HDIM - 1);
        r2t[i] = root2[k2 * NCLS + c2];
    }
}

// ============================================================
// layer-2 messages, edge-parallel: thread per (edge-slot k, class c).
// ============================================================
__global__ __launch_bounds__(256) void msg2_kernel(const float* __restrict__ h,
                                                   const float* __restrict__ w2t,
                                                   const int* __restrict__ d_sr,
                                                   const float* __restrict__ d_norm,
                                                   float* __restrict__ m2) {
    int idx = blockIdx.x * blockDim.x + threadIdx.x;   // NEDGE*8 exact
    int k = idx >> 3;
    int c = idx & (NCLS - 1);
    int pk = d_sr[k];
    float nm = d_norm[k];
    int src = pk & 0xFFFF;
    int r   = pk >> 16;
    const float4* __restrict__ hp = (const float4*)h + src * 4;
    const float4* __restrict__ wp = (const float4*)w2t + (r * NCLS + c) * 4;
    float a = 0.f;
#pragma unroll
    for (int qq = 0; qq < 4; ++qq) {
        float4 hv = hp[qq];
        float4 wv = wp[qq];
        a = fmaf(hv.x, wv.x, a);
        a = fmaf(hv.y, wv.y, a);
        a = fmaf(hv.z, wv.z, a);
        a = fmaf(hv.w, wv.w, a);
    }
    m2[idx] = nm * a;
}

// ============================================================
// layer-2 gather: thread per (dst, c); sequential m2 reads;
// fused root2 + bias2 + log_softmax (8-lane shfl).
// ============================================================
__global__ __launch_bounds__(256) void gather2_kernel(const float* __restrict__ m2,
                                                      const float* __restrict__ h,
                                                      const float* __restrict__ r2t,
                                                      const int* __restrict__ offs_d,
                                                      const int* __restrict__ cnt_d,
                                                      const float* __restrict__ bias2,
                                                      float* __restrict__ out) {
    int idx = blockIdx.x * blockDim.x + threadIdx.x;
    if (idx >= NNODES * NCLS) return;
    int dst = idx >> 3;
    int c   = idx & (NCLS - 1);
    int k0 = offs_d[dst];
    int k1 = k0 + cnt_d[dst];
    float acc = 0.f;
    for (int k = k0; k < k1; ++k)
        acc += m2[k * NCLS + c];
    float v = acc + bias2[c];
    const float4* __restrict__ hd = (const float4*)h + dst * 4;
    const float4* __restrict__ rp = (const float4*)r2t + c * 4;
#pragma unroll
    for (int qq = 0; qq < 4; ++qq) {
        float4 hv = hd[qq];
        float4 rv = rp[qq];
        v = fmaf(hv.x, rv.x, v);
        v = fmaf(hv.y, rv.y, v);
        v = fmaf(hv.z, rv.z, v);
        v = fmaf(hv.w, rv.w, v);
    }
    float mx = v;
    mx = fmaxf(mx, __shfl_xor(mx, 1));
    mx = fmaxf(mx, __shfl_xor(mx, 2));
    mx = fmaxf(mx, __shfl_xor(mx, 4));
    float s = expf(v - mx);
    s += __shfl_xor(s, 1);
    s += __shfl_xor(s, 2);
    s += __shfl_xor(s, 4);
    out[idx] = v - mx - logf(s);
}

// ============================================================
// fallback (flat atomic path; needs ~23.3 MB)
// ============================================================
__global__ __launch_bounds__(256) void degcnt_fb(const int* __restrict__ ei,
                                                 const int* __restrict__ et,
                                                 int* __restrict__ deg) {
    int e = blockIdx.x * blockDim.x + threadIdx.x;
    if (e >= NEDGE) return;
    atomicAdd(&deg[ei[NEDGE + e] * NREL + et[e]], 1);
}

__global__ __launch_bounds__(256) void layer1_flat(const int* __restrict__ ei,
                                                   const int* __restrict__ et,
                                                   const float* __restrict__ basis1,
                                                   const float* __restrict__ comp1,
                                                   const int* __restrict__ deg,
                                                   float* __restrict__ h) {
    long long idx = (long long)blockIdx.x * blockDim.x + threadIdx.x;
    if (idx >= (long long)NEDGE * HDIM) return;
    int e  = (int)(idx >> 4);
    int hh = (int)(idx & (HDIM - 1));
    int src = ei[e];
    int dst = ei[NEDGE + e];
    int r   = et[e];
    float norm = 1.0f / (float)deg[dst * NREL + r];
    const float* __restrict__ cp = comp1 + r * NBASIS;
    float acc = 0.f;
#pragma unroll
    for (int b = 0; b < NBASIS; ++b)
        acc += cp[b] * basis1[(b * NNODES + src) * HDIM + hh];
    atomicAdd(&h[dst * HDIM + hh], norm * acc);
}

__global__ __launch_bounds__(256) void relu_kernel(float* __restrict__ h,
                                                   const float* __restrict__ root1,
                                                   const float* __restrict__ bias1) {
    int i = blockIdx.x * blockDim.x + threadIdx.x;
    if (i >= NNODES * HDIM) return;
    float v = h[i] + root1[i] + bias1[i & (HDIM - 1)];
    h[i] = v > 0.f ? v : 0.f;
}

__global__ __launch_bounds__(256) void layer2_flat(const int* __restrict__ ei,
                                                   const int* __restrict__ et,
                                                   const float* __restrict__ h,
                                                   const float* __restrict__ w2t,
                                                   const int* __restrict__ deg,
                                                   float* __restrict__ out_tmp) {
    long long idx = (long long)blockIdx.x * blockDim.x + threadIdx.x;
    if (idx >= (long long)NEDGE * NCLS) return;
    int e = (int)(idx >> 3);
    int c = (int)(idx & (NCLS - 1));
    int src = ei[e];
    int dst = ei[NEDGE + e];
    int r   = et[e];
    float norm = 1.0f / (float)deg[dst * NREL + r];
    const float4* __restrict__ hp = (const float4*)h + src * 4;
    const float4* __restrict__ wp = (const float4*)w2t + (r * NCLS + c) * 4;
    float a = 0.f;
#pragma unroll
    for (int qq = 0; qq < 4; ++qq) {
        float4 hv = hp[qq];
        float4 wv = wp[qq];
        a = fmaf(hv.x, wv.x, a);
        a = fmaf(hv.y, wv.y, a);
        a = fmaf(hv.z, wv.z, a);
        a = fmaf(hv.w, wv.w, a);
    }
    atomicAdd(&out_tmp[dst * NCLS + c], norm * a);
}

__global__ __launch_bounds__(256) void final_kernel(const float* __restrict__ out_tmp,
                                                    const float* __restrict__ h,
                                                    const float* __restrict__ root2,
                                                    const float* __restrict__ bias2,
                                                    float* __restrict__ out) {
    int n = blockIdx.x * blockDim.x + threadIdx.x;
    if (n >= NNODES) return;
    float hv[HDIM];
#pragma unroll
    for (int i = 0; i < HDIM; ++i) hv[i] = h[n * HDIM + i];
    float v[NCLS];
    float mx = -1e30f;
#pragma unroll
    for (int c = 0; c < NCLS; ++c) {
        float acc = out_tmp[n * NCLS + c] + bias2[c];
#pragma unroll
        for (int i = 0; i < HDIM; ++i) acc += hv[i] * root2[i * NCLS + c];
        v[c] = acc;
        mx = fmaxf(mx, acc);
    }
    float s = 0.f;
#pragma unroll
    for (int c = 0; c < NCLS; ++c) s += expf(v[c] - mx);
    float ls = logf(s);
#pragma unroll
    for (int c = 0; c < NCLS; ++c) out[n * NCLS + c] = v[c] - mx - ls;
}

extern "C" void kernel_launch(void* const* d_in, const int* in_sizes, int n_in,
                              void* d_out, int out_size, void* d_ws, size_t ws_size,
                              hipStream_t stream) {
    const int*   ei     = (const int*)d_in[0];
    const int*   et     = (const int*)d_in[1];
    const float* basis1 = (const float*)d_in[2];
    const float* comp1  = (const float*)d_in[3];
    const float* root1  = (const float*)d_in[4];
    const float* bias1  = (const float*)d_in[5];
    const float* basis2 = (const float*)d_in[6];
    const float* comp2  = (const float*)d_in[7];
    const float* root2  = (const float*)d_in[8];
    const float* bias2  = (const float*)d_in[9];
    float* out = (float*)d_out;

    // ---------- primary layout (4-byte words; int2/uint2 at even offsets) ----------
    int*      gcur_s  = (int*)d_ws;                            // NPART
    int*      gcur_d  = gcur_s + NPART;                        // NPART
    int*      gcnt    = gcur_d + NPART;                        // 4
    unsigned* comp_pk = (unsigned*)(gcnt + 4);                 // NREL*CROW2 = 1800 -> 2588 (even)
    int2*  stg_d  = (int2*)(comp_pk + NREL * CROW2);           // NPART*CAPSTG int2
    int2*  stg_s  = stg_d + (size_t)NPART * CAPSTG;            // NPART*CAPSTG int2
    int*   d_sr   = (int*)(stg_s + (size_t)NPART * CAPSTG);    // E
    float* d_norm = (float*)(d_sr + NEDGE);                    // E
    int*   sB     = (int*)(d_norm + NEDGE);                    // E
    int*   s_k    = sB + NEDGE;                                // E
    int*   offs_s = s_k + NEDGE;                               // N
    int*   cnt_s  = offs_s + NNODES;                           // N
    int*   offs_d = cnt_s + NNODES;                            // N
    int*   cnt_d  = offs_d + NNODES;                           // N
    unsigned* m1  = (unsigned*)(cnt_d + NNODES);               // E*8 words (E*16 f16)
    float* m2     = (float*)m1;                                // E*8 f32 aliases (m1 dead)
    float* h      = (float*)(m1 + (size_t)NEDGE * 8);          // N*H
    float* w2t    = h + (size_t)NNODES * HDIM;                 // R*H*C
    float* r2t    = w2t + (size_t)NREL * HDIM * NCLS;          // H*C
    size_t total_words = 2 * (size_t)NPART + 4 + NREL * CROW2 +
                         4 * (size_t)NPART * CAPSTG +
                         4 * (size_t)NEDGE + 4 * (size_t)NNODES +
                         (size_t)NEDGE * 8 + (size_t)NNODES * HDIM +
                         (size_t)NREL * HDIM * NCLS + HDIM * NCLS;

    if (ws_size >= total_words * sizeof(float)) {
        initc_kernel<<<8, 256, 0, stream>>>(gcur_s, gcur_d, gcnt, comp1, comp_pk);
        p1d_kernel<<<P1BLK, 256, 0, stream>>>(ei, et, gcur_d, stg_d);
        p2d_kernel<<<NPART - 1, 256, 0, stream>>>(gcur_d, stg_d, gcur_s, stg_s, gcnt,
                                                  d_sr, d_norm, offs_d, cnt_d);
        p2s_kernel<<<NPART - 1, 256, 0, stream>>>(gcur_s, stg_s, gcnt, sB, s_k, offs_s, cnt_s);

        msg1_lds<<<NNODES / GS, 256, 0, stream>>>(basis1, comp_pk, offs_s, cnt_s, sB, s_k, m1);
        gather1_flat<<<(NNODES * 4 + 255) / 256, 256, 0, stream>>>(
            m1, d_norm, offs_d, cnt_d, root1, bias1, h);
        w2_kernel<<<(NREL * HDIM * NCLS + 255) / 256, 256, 0, stream>>>(basis2, comp2, root2,
                                                                        w2t, r2t);
        msg2_kernel<<<(NEDGE * NCLS) / 256, 256, 0, stream>>>(h, w2t, d_sr, d_norm, m2);
        gather2_kernel<<<(NNODES * NCLS + 255) / 256, 256, 0, stream>>>(
            m2, h, r2t, offs_d, cnt_d, bias2, out);
        return;
    }

    // ---------- fallback: flat atomic path (~23.3 MB) ----------
    {
        int*   deg_f   = (int*)d_ws;                               // N*R  (zero)
        float* h_f     = (float*)(deg_f + (size_t)NNODES * NREL);  // N*H  (zero)
        float* out_tmp = h_f + (size_t)NNODES * HDIM;              // N*C  (zero)
        size_t zw = (size_t)NNODES * NREL + NNODES * HDIM + NNODES * NCLS;
        float* w2t_f   = out_tmp + (size_t)NNODES * NCLS;          // R*H*C
        float* r2t_f   = w2t_f + (size_t)NREL * HDIM * NCLS;       // H*C

        (void)hipMemsetAsync(d_ws, 0, zw * sizeof(float), stream);
        degcnt_fb<<<(NEDGE + 255) / 256, 256, 0, stream>>>(ei, et, deg_f);
        layer1_flat<<<((size_t)NEDGE * HDIM + 255) / 256, 256, 0, stream>>>(
            ei, et, basis1, comp1, deg_f, h_f);
        relu_kernel<<<(NNODES * HDIM + 255) / 256, 256, 0, stream>>>(h_f, root1, bias1);
        w2_kernel<<<(NREL * HDIM * NCLS + 255) / 256, 256, 0, stream>>>(basis2, comp2, root2,
                                                                        w2t_f, r2t_f);
        layer2_flat<<<((size_t)NEDGE * NCLS + 255) / 256, 256, 0, stream>>>(
            ei, et, h_f, w2t_f, deg_f, out_tmp);
        final_kernel<<<(NNODES + 255) / 256, 256, 0, stream>>>(out_tmp, h_f, root2, bias2, out);
    }
}